// Round 11
// baseline (470.300 us; speedup 1.0000x reference)
//
#include <hip/hip_runtime.h>

#define N_PTS 4096
#define KNBR 40
#define BATCH 4

typedef __attribute__((ext_vector_type(8))) short bf16x8;
typedef __attribute__((ext_vector_type(4))) float f32x4;

__device__ __forceinline__ float lrelu(float v) { return v > 0.0f ? v : 0.2f * v; }

__device__ __forceinline__ short bf16_rn(float f) {
    unsigned u = __float_as_uint(f);
    unsigned r = (u + 0x7FFFu + ((u >> 16) & 1u)) >> 16;
    return (short)r;
}
__device__ __forceinline__ float bf16f(short h) {
    return __uint_as_float(((unsigned)(unsigned short)h) << 16);
}
__device__ __forceinline__ unsigned packbf(float v) {
    short h = bf16_rn(v);
    float r = v - bf16f(h);
    short l = bf16_rn(r);
    return (((unsigned)(unsigned short)h) << 16) | (unsigned)(unsigned short)l;
}
// truncate-hi split: hi = trunc(v), lo = trunc(v - hi). err(hi+lo) ~ 2^-16|v|
__device__ __forceinline__ unsigned pack_trunc(float v) {
    unsigned u = __float_as_uint(v);
    unsigned hi = u & 0xFFFF0000u;
    float r = v - __uint_as_float(hi);
    return hi | (__float_as_uint(r) >> 16);
}

// ---------------- KNN: exact top-40, 2 points/block (shared candidate sweep) ----------------
// Select per point: radix bin select on top-12 bits (direct hist layout; rotated chunk-sum reads)
// + exact candidate rank for the threshold bin.
#define KNN_SELECT(OV, PT)                                                                      \
    {                                                                                           \
        __syncthreads();  /* protect hist/cov reuse from previous pass */                       \
        _Pragma("unroll")                                                                       \
        for (int j = 0; j < 16; ++j) hist[t + j * 256] = 0;                                     \
        if (t < 8) sh[t] = 0;                                                                   \
        __syncthreads();                                                                        \
        _Pragma("unroll")                                                                       \
        for (int j = 0; j < 16; ++j) atomicAdd(&hist[OV[j] >> 20], 1u);                         \
        __syncthreads();                                                                        \
        unsigned cs = 0;                                                                        \
        {                                                                                       \
            const int rot = (t >> 1) & 15;                                                      \
            _Pragma("unroll")                                                                   \
            for (int q = 0; q < 16; ++q) cs += hist[t * 16 + ((q + rot) & 15)];                 \
        }                                                                                       \
        unsigned val = cs;                                                                      \
        _Pragma("unroll")                                                                       \
        for (int off = 1; off < 64; off <<= 1) {                                                \
            unsigned o = __shfl_down(val, off, 64);                                             \
            if (lane + off < 64) val += o;                                                      \
        }                                                                                       \
        if (lane == 0) wtot[wv] = val;                                                          \
        __syncthreads();                                                                        \
        unsigned above_w = 0;                                                                   \
        for (int q = wv + 1; q < 4; ++q) above_w += wtot[q];                                    \
        unsigned Sincl = val + above_w;                                                         \
        unsigned excl = Sincl - cs;                                                             \
        if (excl < KNBR && Sincl >= KNBR) { sh[0] = t; sh[1] = (int)excl; }                     \
        __syncthreads();                                                                        \
        if (t == 0) {                                                                           \
            int tstar = sh[0];                                                                  \
            unsigned run = (unsigned)sh[1];                                                     \
            int B1s = -1; unsigned hcnt = 0;                                                    \
            for (int q = 15; q >= 0; --q) {                                                     \
                unsigned h = hist[tstar * 16 + q];                                              \
                if (run + h >= KNBR) { B1s = tstar * 16 + q; hcnt = h; break; }                 \
                run += h;                                                                       \
            }                                                                                   \
            sh[0] = B1s; sh[1] = (int)run;                                                      \
            sh[7] = KNBR - (int)run;                                                            \
            sh[2] = ((int)hcnt > KNBR - (int)run) ? 1 : 0;                                      \
        }                                                                                       \
        __syncthreads();                                                                        \
        const unsigned B1 = (unsigned)sh[0];                                                    \
        const int needRef = sh[2];                                                              \
        const int R1 = sh[7];                                                                   \
        const int nab = sh[1];                                                                  \
        _Pragma("unroll")                                                                       \
        for (int j = 0; j < 16; ++j) {                                                          \
            unsigned bb = OV[j] >> 20;                                                          \
            if (bb > B1) { int p_ = atomicAdd(&sh[3], 1); idxo[(PT) * KNBR + p_] = t + j * 256; } \
            else if (bb == B1) {                                                                \
                if (!needRef) { int p_ = atomicAdd(&sh[3], 1); idxo[(PT) * KNBR + p_] = t + j * 256; } \
                else { int q_ = atomicAdd(&sh[6], 1); if (q_ < 2048) { cov[q_] = OV[j]; cidx[q_] = t + j * 256; } } \
            }                                                                                   \
        }                                                                                       \
        if (needRef) {                                                                          \
            __syncthreads();                                                                    \
            const int C = sh[6] < 2048 ? sh[6] : 2048;                                          \
            for (int j = t; j < C; j += 256) {                                                  \
                unsigned myv = cov[j]; int myi = cidx[j];                                       \
                int rank = 0;                                                                   \
                for (int q = 0; q < C; ++q) {                                                   \
                    unsigned v = cov[q];                                                        \
                    rank += (v > myv || (v == myv && cidx[q] < myi)) ? 1 : 0;                   \
                }                                                                               \
                if (rank < R1) idxo[(PT) * KNBR + nab + rank] = myi;                            \
            }                                                                                   \
        }                                                                                       \
    }

__global__ __launch_bounds__(256) void knn_kernel(const float* __restrict__ x, int* __restrict__ idxo)
{
    const int t = threadIdx.x;
    const int pt0 = blockIdx.x * 2;
    const int b = pt0 >> 12, n0 = pt0 & 4095;
    const float* xb = x + b * 3 * N_PTS;
    const int lane = t & 63, wv = t >> 6;

    __shared__ unsigned hist[4096];
    __shared__ unsigned wtot[4];
    __shared__ int sh[8];
    unsigned* cov = hist;
    int* cidx = (int*)(hist + 2048);

    const float c00 = xb[n0],     c01 = xb[N_PTS + n0],     c02 = xb[2 * N_PTS + n0];
    const float c10 = xb[n0 + 1], c11 = xb[N_PTS + n0 + 1], c12 = xb[2 * N_PTS + n0 + 1];
    const float cc0 = c00 * c00 + c01 * c01 + c02 * c02;
    const float cc1 = c10 * c10 + c11 * c11 + c12 * c12;

    unsigned ov0[16], ov1[16];
#pragma unroll
    for (int j = 0; j < 16; ++j) {
        int m = t + j * 256;
        float a0 = xb[m], a1 = xb[N_PTS + m], a2 = xb[2 * N_PTS + m];
        float aa = a0 * a0 + a1 * a1 + a2 * a2;
        float d0 = 2.0f * (c00 * a0 + c01 * a1 + c02 * a2) - cc0 - aa;
        float d1 = 2.0f * (c10 * a0 + c11 * a1 + c12 * a2) - cc1 - aa;
        unsigned u0 = __float_as_uint(d0);
        ov0[j] = (u0 & 0x80000000u) ? ~u0 : (u0 | 0x80000000u);
        unsigned u1 = __float_as_uint(d1);
        ov1[j] = (u1 & 0x80000000u) ? ~u1 : (u1 | 0x80000000u);
    }

    KNN_SELECT(ov0, pt0)
    KNN_SELECT(ov1, pt0 + 1)
}

// ---------------- Layer 1 via MFMA: conv1(6->64 VALU) + conv2(64->64 MFMA) + in-reg max, 2 pts/block --------
__global__ __launch_bounds__(256) void layer1_mfma_kernel(const float* __restrict__ x, const int* __restrict__ idx,
    const float* __restrict__ W1, const float* __restrict__ s1, const float* __restrict__ b1,
    const short* __restrict__ w2h, const short* __restrict__ w2l,
    const float* __restrict__ s2, const float* __restrict__ b2,
    unsigned* __restrict__ x1p)
{
    const int t = threadIdx.x;
    const int pt0 = blockIdx.x * 2;
    const int b = pt0 >> 12;
    const float* xb = x + b * 3 * N_PTS;
    const int lane = t & 63, w = t >> 6;
    const int cn = lane & 15, kg = lane >> 4;

    __shared__ int idxs[80];
    __shared__ float w1t[384];          // [6][64] transposed W1
    __shared__ float ctrv[2][64];
    __shared__ float nbrc[80][4];
    __shared__ float Abuf[5808];
    short* A_hi = (short*)Abuf;
    short* A_lo = A_hi + 80 * 72;

    if (t < 80) idxs[t] = idx[pt0 * KNBR + t];
    if (t < 64) {
#pragma unroll
        for (int j = 0; j < 6; ++j) w1t[j * 64 + t] = W1[t * 6 + j];
    }
    __syncthreads();
    if (t < 240) { int k = t / 3, j = t % 3; nbrc[k][j] = xb[j * N_PTS + idxs[k]]; }
    if (t < 128) {
        int p = t >> 6, o = t & 63;
        int n = (pt0 + p) & 4095;
        float cx = xb[n], cy = xb[N_PTS + n], cz = xb[2 * N_PTS + n];
        ctrv[p][o] = (w1t[192 + o] - w1t[o]) * cx + (w1t[256 + o] - w1t[64 + o]) * cy
                   + (w1t[320 + o] - w1t[128 + o]) * cz;
    }
    bf16x8 bh[2], bl[2];
#pragma unroll
    for (int kc = 0; kc < 2; ++kc) {
        int off = (w * 16 + cn) * 64 + kc * 32 + kg * 8;
        bh[kc] = *(const bf16x8*)(w2h + off);
        bl[kc] = *(const bf16x8*)(w2l + off);
    }
    __syncthreads();
    {
        const int o = t & 63;
        const float w0 = w1t[o], w1v = w1t[64 + o], w2v = w1t[128 + o];
        const float sv = s1[o], bv = b1[o];
        const float cv0 = ctrv[0][o], cv1 = ctrv[1][o];
#pragma unroll
        for (int r = 0; r < 20; ++r) {
            int k = (t >> 6) + r * 4;
            float v = w0 * nbrc[k][0] + w1v * nbrc[k][1] + w2v * nbrc[k][2] + (k >= KNBR ? cv1 : cv0);
            v = lrelu(v * sv + bv);
            unsigned u = __float_as_uint(v);
            unsigned hi = u & 0xFFFF0000u;
            A_hi[k * 72 + o] = (short)(u >> 16);
            float rr = v - __uint_as_float(hi);
            A_lo[k * 72 + o] = (short)(__float_as_uint(rr) >> 16);
        }
    }
    __syncthreads();
    f32x4 acc[5];
#pragma unroll
    for (int mt = 0; mt < 5; ++mt) {
        f32x4 a = {0.f, 0.f, 0.f, 0.f};
#pragma unroll
        for (int kc = 0; kc < 2; ++kc) {
            int ao = (mt * 16 + cn) * 72 + kc * 32 + kg * 8;
            bf16x8 ah = *(const bf16x8*)(A_hi + ao);
            bf16x8 al = *(const bf16x8*)(A_lo + ao);
            a = __builtin_amdgcn_mfma_f32_16x16x32_bf16(al, bh[kc], a, 0, 0, 0);
            a = __builtin_amdgcn_mfma_f32_16x16x32_bf16(ah, bl[kc], a, 0, 0, 0);
            a = __builtin_amdgcn_mfma_f32_16x16x32_bf16(ah, bh[kc], a, 0, 0, 0);
        }
        acc[mt] = a;
    }
    const int o1 = w * 16 + cn;
    const float sB = s2[o1], bB = b2[o1];
    float m0 = -1e30f, m1 = -1e30f;
#pragma unroll
    for (int mt = 0; mt < 5; ++mt)
#pragma unroll
        for (int reg = 0; reg < 4; ++reg) {
            int row = mt * 16 + kg * 4 + reg;
            float v = lrelu(acc[mt][reg] * sB + bB);
            if (row < KNBR) m0 = fmaxf(m0, v); else m1 = fmaxf(m1, v);
        }
    m0 = fmaxf(m0, __shfl_xor(m0, 16, 64));
    m0 = fmaxf(m0, __shfl_xor(m0, 32, 64));
    m1 = fmaxf(m1, __shfl_xor(m1, 16, 64));
    m1 = fmaxf(m1, __shfl_xor(m1, 32, 64));
    if (kg == 0) {
        x1p[pt0 * 64 + o1] = packbf(m0);
        x1p[(pt0 + 1) * 64 + o1] = packbf(m1);
    }
}

// ---------------- prep: edge-conv + W2 weights -> bf16 hi/lo + ctr-weight transpose ----------------
__global__ __launch_bounds__(256) void prep_kernel(const float* __restrict__ W2, const float* __restrict__ W3,
    const float* __restrict__ W4, const float* __restrict__ W5,
    short* __restrict__ w2h, short* __restrict__ w2l,
    short* __restrict__ w3h, short* __restrict__ w3l,
    short* __restrict__ w4h, short* __restrict__ w4l,
    short* __restrict__ w5h, short* __restrict__ w5l,
    float* __restrict__ wdt3, float* __restrict__ wdt5)
{
    int e = blockIdx.x * 256 + threadIdx.x;   // 4096
    int o = e >> 6, i = e & 63;
    float a = W3[o * 128 + i];
    short h = bf16_rn(a);
    w3h[e] = h; w3l[e] = bf16_rn(a - bf16f(h));
    wdt3[i * 64 + o] = W3[o * 128 + 64 + i] - a;
    float c = W4[o * 64 + i];
    h = bf16_rn(c);
    w4h[e] = h; w4l[e] = bf16_rn(c - bf16f(h));
    float d = W5[o * 128 + i];
    h = bf16_rn(d);
    w5h[e] = h; w5l[e] = bf16_rn(d - bf16f(h));
    wdt5[i * 64 + o] = W5[o * 128 + 64 + i] - d;
    float e2 = W2[o * 64 + i];
    h = bf16_rn(e2);
    w2h[e] = h; w2l[e] = bf16_rn(e2 - bf16f(h));
}

// ---------------- prep2: W6/W7(slice)/W8/W9 -> split bf16 hi/lo ----------------
__global__ __launch_bounds__(256) void prep2_kernel(const float* __restrict__ W6, const float* __restrict__ W7,
    const float* __restrict__ W8, const float* __restrict__ W9,
    short* __restrict__ w6h, short* __restrict__ w6l,
    short* __restrict__ w7h, short* __restrict__ w7l,
    short* __restrict__ w8h, short* __restrict__ w8l,
    short* __restrict__ w9h, short* __restrict__ w9l)
{
    int e = blockIdx.x * 256 + threadIdx.x;
    float v; short* dh; short* dl; int di;
    if (e < 196608) {
        v = W6[e]; dh = w6h; dl = w6l; di = e;
    } else if (e < 294912) {
        int ee = e - 196608;
        int o = ee / 192, k = ee - o * 192;
        v = W7[o * 1216 + 1024 + k]; dh = w7h; dl = w7l; di = ee;
    } else if (e < 425984) {
        int ee = e - 294912;
        v = W8[ee]; dh = w8h; dl = w8l; di = ee;
    } else if (e < 442368) {
        int ee = e - 425984;
        int o = ee >> 8, k = ee & 255;
        v = (o < 63) ? W9[o * 256 + k] : 0.0f;
        dh = w9h; dl = w9l; di = ee;
    } else return;
    short h = bf16_rn(v);
    dh[di] = h; dl[di] = bf16_rn(v - bf16f(h));
}

// ---------------- Edge layers via MFMA (split-bf16), packed input, in-reg max, 2 points/block, M=80 --------
template<int HAS2>
__global__ __launch_bounds__(256) void edge_mfma_kernel(const unsigned* __restrict__ srcp, const int* __restrict__ idx,
    const short* __restrict__ wah, const short* __restrict__ wal, const float* __restrict__ wdt,
    const float* __restrict__ sa, const float* __restrict__ ba,
    const short* __restrict__ wbh, const short* __restrict__ wbl,
    const float* __restrict__ sb, const float* __restrict__ bb,
    unsigned* __restrict__ xpout)
{
    const int t = threadIdx.x;
    const int pt0 = blockIdx.x * 2;
    const int b = pt0 >> 12;
    const int lane = t & 63, w = t >> 6;
    const int cn = lane & 15, kg = lane >> 4;

    __shared__ int idxs[80];
    __shared__ float ctr1[2][64];
    __shared__ float part[2][2][64];
    __shared__ float Abuf[5808];
    short* A_hi = (short*)Abuf;
    short* A_lo = A_hi + 80 * 72;

    if (t < 80) idxs[t] = idx[pt0 * KNBR + t];
    if (t >= 128) {
        int p = (t >> 6) & 1; int i = t & 63;
        unsigned u = srcp[(pt0 + p) * 64 + i];
        ctr1[p][i] = bf16f((short)(u >> 16)) + bf16f((short)u);
    }
    __syncthreads();

    bf16x8 bh[2], bl[2];
#pragma unroll
    for (int kc = 0; kc < 2; ++kc) {
        int off = (w * 16 + cn) * 64 + kc * 32 + kg * 8;
        bh[kc] = *(const bf16x8*)(wah + off);
        bl[kc] = *(const bf16x8*)(wal + off);
    }

    // gather packed neighbors -> unpack to hi/lo LDS planes (2 shifts/elem)
    {
        const int r0 = t >> 4, c4 = (t & 15) * 4;
#pragma unroll
        for (int r = 0; r < 5; ++r) {
            int row = r * 16 + r0;
            uint4 v = *(const uint4*)(srcp + (size_t)(b * N_PTS + idxs[row]) * 64 + c4);
            short4 h, l;
            h.x = (short)(v.x >> 16); l.x = (short)v.x;
            h.y = (short)(v.y >> 16); l.y = (short)v.y;
            h.z = (short)(v.z >> 16); l.z = (short)v.z;
            h.w = (short)(v.w >> 16); l.w = (short)v.w;
            *(short4*)(A_hi + row * 72 + c4) = h;
            *(short4*)(A_lo + row * 72 + c4) = l;
        }
    }
    // ctrv partials across all 256 threads (32 FMAs each)
    {
        int p = t >> 7, half = (t >> 6) & 1, o = t & 63;
        const float* wp = wdt + half * 32 * 64 + o;
        float s = 0.0f;
#pragma unroll 8
        for (int i = 0; i < 32; ++i) s = fmaf(wp[i * 64], ctr1[p][half * 32 + i], s);
        part[p][half][o] = s;
    }
    __syncthreads();

    f32x4 acc[5];
#pragma unroll
    for (int mt = 0; mt < 5; ++mt) {
        f32x4 a = {0.f, 0.f, 0.f, 0.f};
#pragma unroll
        for (int kc = 0; kc < 2; ++kc) {
            int ao = (mt * 16 + cn) * 72 + kc * 32 + kg * 8;
            bf16x8 ah = *(const bf16x8*)(A_hi + ao);
            bf16x8 al = *(const bf16x8*)(A_lo + ao);
            a = __builtin_amdgcn_mfma_f32_16x16x32_bf16(al, bh[kc], a, 0, 0, 0);
            a = __builtin_amdgcn_mfma_f32_16x16x32_bf16(ah, bl[kc], a, 0, 0, 0);
            a = __builtin_amdgcn_mfma_f32_16x16x32_bf16(ah, bh[kc], a, 0, 0, 0);
        }
        acc[mt] = a;
    }

    const int o1 = w * 16 + cn;
    const float cv0 = part[0][0][o1] + part[0][1][o1];
    const float cv1 = part[1][0][o1] + part[1][1][o1];
    const float sA = sa[o1], bA = ba[o1];

    if (HAS2) {
        __syncthreads();   // all MFMA reads of A done before overwrite
#pragma unroll
        for (int mt = 0; mt < 5; ++mt) {
#pragma unroll
            for (int reg = 0; reg < 4; ++reg) {
                int row = mt * 16 + kg * 4 + reg;
                float v = lrelu((acc[mt][reg] + (row >= KNBR ? cv1 : cv0)) * sA + bA);
                unsigned u = __float_as_uint(v);
                unsigned hi = u & 0xFFFF0000u;
                A_hi[row * 72 + o1] = (short)(u >> 16);
                float rr = v - __uint_as_float(hi);
                A_lo[row * 72 + o1] = (short)(__float_as_uint(rr) >> 16);
            }
        }
        __syncthreads();
#pragma unroll
        for (int kc = 0; kc < 2; ++kc) {
            int off = (w * 16 + cn) * 64 + kc * 32 + kg * 8;
            bh[kc] = *(const bf16x8*)(wbh + off);
            bl[kc] = *(const bf16x8*)(wbl + off);
        }
#pragma unroll
        for (int mt = 0; mt < 5; ++mt) {
            f32x4 a = {0.f, 0.f, 0.f, 0.f};
#pragma unroll
            for (int kc = 0; kc < 2; ++kc) {
                int ao = (mt * 16 + cn) * 72 + kc * 32 + kg * 8;
                bf16x8 ah = *(const bf16x8*)(A_hi + ao);
                bf16x8 al = *(const bf16x8*)(A_lo + ao);
                a = __builtin_amdgcn_mfma_f32_16x16x32_bf16(al, bh[kc], a, 0, 0, 0);
                a = __builtin_amdgcn_mfma_f32_16x16x32_bf16(ah, bl[kc], a, 0, 0, 0);
                a = __builtin_amdgcn_mfma_f32_16x16x32_bf16(ah, bh[kc], a, 0, 0, 0);
            }
            acc[mt] = a;
        }
        const float sB = sb[o1], bB = bb[o1];
        float m0 = -1e30f, m1 = -1e30f;
#pragma unroll
        for (int mt = 0; mt < 5; ++mt)
#pragma unroll
            for (int reg = 0; reg < 4; ++reg) {
                int row = mt * 16 + kg * 4 + reg;
                float v = lrelu(acc[mt][reg] * sB + bB);
                if (row < KNBR) m0 = fmaxf(m0, v); else m1 = fmaxf(m1, v);
            }
        m0 = fmaxf(m0, __shfl_xor(m0, 16, 64));
        m0 = fmaxf(m0, __shfl_xor(m0, 32, 64));
        m1 = fmaxf(m1, __shfl_xor(m1, 16, 64));
        m1 = fmaxf(m1, __shfl_xor(m1, 32, 64));
        if (kg == 0) {
            xpout[pt0 * 64 + o1] = packbf(m0);
            xpout[(pt0 + 1) * 64 + o1] = packbf(m1);
        }
    } else {
        float m0 = -1e30f, m1 = -1e30f;
#pragma unroll
        for (int mt = 0; mt < 5; ++mt)
#pragma unroll
            for (int reg = 0; reg < 4; ++reg) {
                int row = mt * 16 + kg * 4 + reg;
                float v = lrelu((acc[mt][reg] + (row >= KNBR ? cv1 : cv0)) * sA + bA);
                if (row < KNBR) m0 = fmaxf(m0, v); else m1 = fmaxf(m1, v);
            }
        m0 = fmaxf(m0, __shfl_xor(m0, 16, 64));
        m0 = fmaxf(m0, __shfl_xor(m0, 32, 64));
        m1 = fmaxf(m1, __shfl_xor(m1, 16, 64));
        m1 = fmaxf(m1, __shfl_xor(m1, 32, 64));
        if (kg == 0) {
            xpout[pt0 * 64 + o1] = packbf(m0);
            xpout[(pt0 + 1) * 64 + o1] = packbf(m1);
        }
    }
}

// ---------------- Split-bf16 MFMA GEMM, fused epilogues ----------------
// MODE 0: conv6 (A=x123p K=192, lrelu, per-block col-max -> gpart)
// MODE 3: conv9 (A=h8p K=256, +b9, transposed fp32 store, col<63)
template<int MODE, int MT, int NT, int KD, int NTOT>
__global__ __launch_bounds__(256) void gemm_mfma(
    const unsigned* __restrict__ A0, const unsigned* __restrict__ A1, const unsigned* __restrict__ A2,
    const short* __restrict__ Bh, const short* __restrict__ Bl,
    const float* __restrict__ sv, const float* __restrict__ bvv,
    const float* __restrict__ extra, void* __restrict__ outp)
{
    const int t = threadIdx.x;
    const int w = t >> 6, lane = t & 63;
    const int cn = lane & 15, kg = lane >> 4;
    const int m0 = blockIdx.x * (MT * 16);
    const int n0 = blockIdx.y * (NT * 64);

    __shared__ __align__(16) short Abuf2[2 * MT * 16 * 40];
    short* A_hi = Abuf2;
    short* A_lo = Abuf2 + MT * 16 * 40;

    f32x4 acc[MT][NT];
#pragma unroll
    for (int mt = 0; mt < MT; ++mt)
#pragma unroll
        for (int nt = 0; nt < NT; ++nt) acc[mt][nt] = (f32x4){0.f, 0.f, 0.f, 0.f};

    for (int kc = 0; kc < KD / 32; ++kc) {
        {
            const int kq = (t & 7) * 4;
            const int r0 = t >> 3;
#pragma unroll
            for (int rr = 0; rr < (MT * 16) / 32; ++rr) {
                int row = r0 + rr * 32;
                int gk = kc * 32 + kq;
                uint4 v;
                if (MODE == 0) {
                    const unsigned* srcp = (gk < 64) ? A0 : ((gk < 128) ? A1 : A2);
                    v = *(const uint4*)(srcp + (size_t)(m0 + row) * 64 + (gk & 63));
                } else {
                    v = *(const uint4*)(A0 + (size_t)(m0 + row) * KD + gk);
                }
                short4 h, l;
                h.x = (short)(v.x >> 16); l.x = (short)v.x;
                h.y = (short)(v.y >> 16); l.y = (short)v.y;
                h.z = (short)(v.z >> 16); l.z = (short)v.z;
                h.w = (short)(v.w >> 16); l.w = (short)v.w;
                *(short4*)(A_hi + row * 40 + kq) = h;
                *(short4*)(A_lo + row * 40 + kq) = l;
            }
        }
        __syncthreads();
        bf16x8 bh[NT], bl[NT];
#pragma unroll
        for (int nt = 0; nt < NT; ++nt) {
            int col = n0 + (w * NT + nt) * 16 + cn;
            int boff = col * KD + kc * 32 + kg * 8;
            bh[nt] = *(const bf16x8*)(Bh + boff);
            bl[nt] = *(const bf16x8*)(Bl + boff);
        }
#pragma unroll
        for (int mt = 0; mt < MT; ++mt) {
            int ao = (mt * 16 + cn) * 40 + kg * 8;
            bf16x8 ah = *(const bf16x8*)(A_hi + ao);
            bf16x8 al = *(const bf16x8*)(A_lo + ao);
#pragma unroll
            for (int nt = 0; nt < NT; ++nt) {
                acc[mt][nt] = __builtin_amdgcn_mfma_f32_16x16x32_bf16(al, bh[nt], acc[mt][nt], 0, 0, 0);
                acc[mt][nt] = __builtin_amdgcn_mfma_f32_16x16x32_bf16(ah, bl[nt], acc[mt][nt], 0, 0, 0);
                acc[mt][nt] = __builtin_amdgcn_mfma_f32_16x16x32_bf16(ah, bh[nt], acc[mt][nt], 0, 0, 0);
            }
        }
        __syncthreads();
    }

    if (MODE == 0) {
        float* gp = (float*)outp;
#pragma unroll
        for (int nt = 0; nt < NT; ++nt) {
            int col = n0 + (w * NT + nt) * 16 + cn;
            float s = sv[col], bb = bvv[col];
            float mx = -1e30f;
#pragma unroll
            for (int mt = 0; mt < MT; ++mt)
#pragma unroll
                for (int r = 0; r < 4; ++r) mx = fmaxf(mx, lrelu(acc[mt][nt][r] * s + bb));
            mx = fmaxf(mx, __shfl_xor(mx, 16, 64));
            mx = fmaxf(mx, __shfl_xor(mx, 32, 64));
            if (kg == 0) gp[blockIdx.x * NTOT + col] = mx;
        }
    } else {
        float* of = (float*)outp;
        const int b = m0 >> 12;
        const int nrow0 = m0 & 4095;
        int col = w * 16 + cn;
        if (col < 63) {
            float bb = bvv[col];
#pragma unroll
            for (int mt = 0; mt < MT; ++mt) {
                float4 o4;
                o4.x = acc[mt][0][0] + bb; o4.y = acc[mt][0][1] + bb;
                o4.z = acc[mt][0][2] + bb; o4.w = acc[mt][0][3] + bb;
                *(float4*)(of + (size_t)(b * 63 + col) * N_PTS + nrow0 + mt * 16 + kg * 4) = o4;
            }
        }
    }
}

// ---------------- MODE 2-style GEMM (contiguous packed A), packed output via LDS transpose ----------------
template<int MODE, int MT, int NT, int KD, int NTOT>
__global__ __launch_bounds__(256) void gemm_mfma_t(
    const unsigned* __restrict__ A0,
    const short* __restrict__ Bh, const short* __restrict__ Bl,
    const float* __restrict__ sv, const float* __restrict__ bvv,
    const float* __restrict__ extra, unsigned* __restrict__ op)
{
    const int t = threadIdx.x;
    const int w = t >> 6, lane = t & 63;
    const int cn = lane & 15, kg = lane >> 4;
    const int m0 = blockIdx.x * (MT * 16);
    const int n0 = blockIdx.y * (NT * 64);

    __shared__ __align__(16) short Abuf2[2 * MT * 16 * 40 > 2 * 16 * 132 * 2 ? 2 * MT * 16 * 40 : 2 * 16 * 132 * 2];
    short* A_hi = Abuf2;
    short* A_lo = Abuf2 + MT * 16 * 40;

    f32x4 acc[MT][NT];
#pragma unroll
    for (int mt = 0; mt < MT; ++mt)
#pragma unroll
        for (int nt = 0; nt < NT; ++nt) acc[mt][nt] = (f32x4){0.f, 0.f, 0.f, 0.f};

    for (int kc = 0; kc < KD / 32; ++kc) {
        {
            const int kq = (t & 7) * 4;
            const int r0 = t >> 3;
#pragma unroll
            for (int rr = 0; rr < (MT * 16) / 32; ++rr) {
                int row = r0 + rr * 32;
                int gk = kc * 32 + kq;
                uint4 v = *(const uint4*)(A0 + (size_t)(m0 + row) * KD + gk);
                short4 h, l;
                h.x = (short)(v.x >> 16); l.x = (short)v.x;
                h.y = (short)(v.y >> 16); l.y = (short)v.y;
                h.z = (short)(v.z >> 16); l.z = (short)v.z;
                h.w = (short)(v.w >> 16); l.w = (short)v.w;
                *(short4*)(A_hi + row * 40 + kq) = h;
                *(short4*)(A_lo + row * 40 + kq) = l;
            }
        }
        __syncthreads();
        bf16x8 bh[NT], bl[NT];
#pragma unroll
        for (int nt = 0; nt < NT; ++nt) {
            int col = n0 + (w * NT + nt) * 16 + cn;
            int boff = col * KD + kc * 32 + kg * 8;
            bh[nt] = *(const bf16x8*)(Bh + boff);
            bl[nt] = *(const bf16x8*)(Bl + boff);
        }
#pragma unroll
        for (int mt = 0; mt < MT; ++mt) {
            int ao = (mt * 16 + cn) * 40 + kg * 8;
            bf16x8 ah = *(const bf16x8*)(A_hi + ao);
            bf16x8 al = *(const bf16x8*)(A_lo + ao);
#pragma unroll
            for (int nt = 0; nt < NT; ++nt) {
                acc[mt][nt] = __builtin_amdgcn_mfma_f32_16x16x32_bf16(al, bh[nt], acc[mt][nt], 0, 0, 0);
                acc[mt][nt] = __builtin_amdgcn_mfma_f32_16x16x32_bf16(ah, bl[nt], acc[mt][nt], 0, 0, 0);
                acc[mt][nt] = __builtin_amdgcn_mfma_f32_16x16x32_bf16(ah, bh[nt], acc[mt][nt], 0, 0, 0);
            }
        }
        __syncthreads();
    }

    unsigned* T = (unsigned*)Abuf2;
    const int b = m0 >> 12;
#pragma unroll
    for (int mt = 0; mt < MT; ++mt) {
#pragma unroll
        for (int nt = 0; nt < NT; ++nt) {
            int col = n0 + (w * NT + nt) * 16 + cn;
            float s = sv[col], bb = bvv[col];
            float cc = (MODE == 1) ? extra[b * 512 + col] : 0.0f;
#pragma unroll
            for (int r = 0; r < 4; ++r) {
                float v = lrelu((acc[mt][nt][r] + cc) * s + bb);
                T[(kg * 4 + r) * 132 + (w * NT + nt) * 16 + cn] = pack_trunc(v);
            }
        }
        __syncthreads();
        {
            int row = t >> 4, c0 = (t & 15) * 8;
            uint4 u0 = *(uint4*)(T + row * 132 + c0);
            uint4 u1 = *(uint4*)(T + row * 132 + c0 + 4);
            int grow = m0 + mt * 16 + row;
            *(uint4*)(op + (size_t)grow * NTOT + n0 + c0) = u0;
            *(uint4*)(op + (size_t)grow * NTOT + n0 + c0 + 4) = u1;
        }
        __syncthreads();
    }
}

// ---------------- MODE 1 GEMM (three packed x-arrays), +c7 epilogue, packed output ----------------
template<int MT, int NT, int KD, int NTOT>
__global__ __launch_bounds__(256) void gemm_mfma_c7(
    const unsigned* __restrict__ A0, const unsigned* __restrict__ A1, const unsigned* __restrict__ A2,
    const short* __restrict__ Bh, const short* __restrict__ Bl,
    const float* __restrict__ sv, const float* __restrict__ bvv,
    const float* __restrict__ extra, unsigned* __restrict__ op)
{
    const int t = threadIdx.x;
    const int w = t >> 6, lane = t & 63;
    const int cn = lane & 15, kg = lane >> 4;
    const int m0 = blockIdx.x * (MT * 16);
    const int n0 = blockIdx.y * (NT * 64);

    __shared__ __align__(16) short Abuf2[2 * MT * 16 * 40 > 2 * 16 * 132 * 2 ? 2 * MT * 16 * 40 : 2 * 16 * 132 * 2];
    short* A_hi = Abuf2;
    short* A_lo = Abuf2 + MT * 16 * 40;

    f32x4 acc[MT][NT];
#pragma unroll
    for (int mt = 0; mt < MT; ++mt)
#pragma unroll
        for (int nt = 0; nt < NT; ++nt) acc[mt][nt] = (f32x4){0.f, 0.f, 0.f, 0.f};

    for (int kc = 0; kc < KD / 32; ++kc) {
        {
            const int kq = (t & 7) * 4;
            const int r0 = t >> 3;
#pragma unroll
            for (int rr = 0; rr < (MT * 16) / 32; ++rr) {
                int row = r0 + rr * 32;
                int gk = kc * 32 + kq;
                const unsigned* srcp = (gk < 64) ? A0 : ((gk < 128) ? A1 : A2);
                uint4 v = *(const uint4*)(srcp + (size_t)(m0 + row) * 64 + (gk & 63));
                short4 h, l;
                h.x = (short)(v.x >> 16); l.x = (short)v.x;
                h.y = (short)(v.y >> 16); l.y = (short)v.y;
                h.z = (short)(v.z >> 16); l.z = (short)v.z;
                h.w = (short)(v.w >> 16); l.w = (short)v.w;
                *(short4*)(A_hi + row * 40 + kq) = h;
                *(short4*)(A_lo + row * 40 + kq) = l;
            }
        }
        __syncthreads();
        bf16x8 bh[NT], bl[NT];
#pragma unroll
        for (int nt = 0; nt < NT; ++nt) {
            int col = n0 + (w * NT + nt) * 16 + cn;
            int boff = col * KD + kc * 32 + kg * 8;
            bh[nt] = *(const bf16x8*)(Bh + boff);
            bl[nt] = *(const bf16x8*)(Bl + boff);
        }
#pragma unroll
        for (int mt = 0; mt < MT; ++mt) {
            int ao = (mt * 16 + cn) * 40 + kg * 8;
            bf16x8 ah = *(const bf16x8*)(A_hi + ao);
            bf16x8 al = *(const bf16x8*)(A_lo + ao);
#pragma unroll
            for (int nt = 0; nt < NT; ++nt) {
                acc[mt][nt] = __builtin_amdgcn_mfma_f32_16x16x32_bf16(al, bh[nt], acc[mt][nt], 0, 0, 0);
                acc[mt][nt] = __builtin_amdgcn_mfma_f32_16x16x32_bf16(ah, bl[nt], acc[mt][nt], 0, 0, 0);
                acc[mt][nt] = __builtin_amdgcn_mfma_f32_16x16x32_bf16(ah, bh[nt], acc[mt][nt], 0, 0, 0);
            }
        }
        __syncthreads();
    }

    unsigned* T = (unsigned*)Abuf2;
    const int b = m0 >> 12;
#pragma unroll
    for (int mt = 0; mt < MT; ++mt) {
#pragma unroll
        for (int nt = 0; nt < NT; ++nt) {
            int col = n0 + (w * NT + nt) * 16 + cn;
            float s = sv[col], bb = bvv[col];
            float cc = extra[b * 512 + col];
#pragma unroll
            for (int r = 0; r < 4; ++r) {
                float v = lrelu((acc[mt][nt][r] + cc) * s + bb);
                T[(kg * 4 + r) * 132 + (w * NT + nt) * 16 + cn] = pack_trunc(v);
            }
        }
        __syncthreads();
        {
            int row = t >> 4, c0 = (t & 15) * 8;
            uint4 u0 = *(uint4*)(T + row * 132 + c0);
            uint4 u1 = *(uint4*)(T + row * 132 + c0 + 4);
            int grow = m0 + mt * 16 + row;
            *(uint4*)(op + (size_t)grow * NTOT + n0 + c0) = u0;
            *(uint4*)(op + (size_t)grow * NTOT + n0 + c0 + 4) = u1;
        }
        __syncthreads();
    }
}

__global__ __launch_bounds__(256) void greduce_kernel(const float* __restrict__ gpart, float* __restrict__ g)
{
    int tid = blockIdx.x * 256 + threadIdx.x;   // 4096
    int b = tid >> 10, o = tid & 1023;
    float m = -1e30f;
    for (int q = 0; q < 32; ++q) m = fmaxf(m, gpart[(b * 32 + q) * 1024 + o]);
    g[tid] = m;
}

__global__ __launch_bounds__(256) void c7_kernel(const float* __restrict__ g, const float* __restrict__ W7,
                                                 float* __restrict__ c7)
{
    int tid = blockIdx.x * 256 + threadIdx.x;   // 2048
    int b = tid >> 9, o = tid & 511;
    const float* gb = g + b * 1024;
    const float* wr = W7 + o * 1216;
    float s = 0.0f;
    for (int i = 0; i < 1024; i += 4) {
        float4 wv4 = *reinterpret_cast<const float4*>(&wr[i]);
        float4 gv4 = *reinterpret_cast<const float4*>(&gb[i]);
        s += wv4.x * gv4.x + wv4.y * gv4.y + wv4.z * gv4.z + wv4.w * gv4.w;
    }
    c7[tid] = s;
}

extern "C" void kernel_launch(void* const* d_in, const int* in_sizes, int n_in,
                              void* d_out, int out_size, void* d_ws, size_t ws_size,
                              hipStream_t stream)
{
    const float* x  = (const float*)d_in[0];
    const float* W1 = (const float*)d_in[1];
    const float* s1 = (const float*)d_in[2];
    const float* b1 = (const float*)d_in[3];
    const float* W2 = (const float*)d_in[4];
    const float* s2 = (const float*)d_in[5];
    const float* b2 = (const float*)d_in[6];
    const float* W3 = (const float*)d_in[7];
    const float* s3 = (const float*)d_in[8];
    const float* b3 = (const float*)d_in[9];
    const float* W4 = (const float*)d_in[10];
    const float* s4 = (const float*)d_in[11];
    const float* b4 = (const float*)d_in[12];
    const float* W5 = (const float*)d_in[13];
    const float* s5 = (const float*)d_in[14];
    const float* b5 = (const float*)d_in[15];
    const float* W6 = (const float*)d_in[16];
    const float* s6 = (const float*)d_in[17];
    const float* b6 = (const float*)d_in[18];
    const float* W7 = (const float*)d_in[19];
    const float* s7 = (const float*)d_in[20];
    const float* b7 = (const float*)d_in[21];
    const float* W8 = (const float*)d_in[22];
    const float* s8 = (const float*)d_in[23];
    const float* b8 = (const float*)d_in[24];
    const float* W9 = (const float*)d_in[25];
    const float* b9 = (const float*)d_in[26];

    char* ws = (char*)d_ws;
    int*      idx   = (int*)(ws);                      // 2.62 MB
    unsigned* x1p   = (unsigned*)(ws + 15204352);
    unsigned* x2p   = (unsigned*)(ws + 19398656);
    unsigned* x3p   = (unsigned*)(ws + 23592960);
    float*    gpart = (float*)(ws + 27787264);
    float*    g     = (float*)(ws + 28311552);
    float*    c7    = (float*)(ws + 28327936);
    short*    w3h   = (short*)(ws + 28336128);
    short*    w3l   = w3h + 4096;
    short*    w4h   = w3h + 8192;
    short*    w4l   = w3h + 12288;
    short*    w5h   = w3h + 16384;
    short*    w5l   = w3h + 20480;
    float*    wdt3  = (float*)(ws + 28385280);
    float*    wdt5  = (float*)(ws + 28401664);
    short*    w6h   = (short*)(ws + 28418048);
    short*    w6l   = (short*)(ws + 28811264);
    short*    w7h   = (short*)(ws + 29204480);
    short*    w7l   = (short*)(ws + 29401088);
    short*    w8h   = (short*)(ws + 29597696);
    short*    w8l   = (short*)(ws + 29859840);
    short*    w9h   = (short*)(ws + 30121984);
    short*    w9l   = (short*)(ws + 30154752);
    short*    w2h   = (short*)(ws + 30187520);
    short*    w2l   = (short*)(ws + 30195712);
    unsigned* h7p   = (unsigned*)(ws + 30408704);      // 33.55 MB -> ends 63963136
    unsigned* h8p   = (unsigned*)(ws);                 // aliases dead early buffers
    float*    outp  = (float*)d_out;

    knn_kernel<<<BATCH * N_PTS / 2, 256, 0, stream>>>(x, idx);
    prep_kernel<<<16, 256, 0, stream>>>(W2, W3, W4, W5, w2h, w2l, w3h, w3l, w4h, w4l, w5h, w5l, wdt3, wdt5);
    prep2_kernel<<<1728, 256, 0, stream>>>(W6, W7, W8, W9, w6h, w6l, w7h, w7l, w8h, w8l, w9h, w9l);
    layer1_mfma_kernel<<<BATCH * N_PTS / 2, 256, 0, stream>>>(x, idx, W1, s1, b1, w2h, w2l, s2, b2, x1p);
    edge_mfma_kernel<1><<<BATCH * N_PTS / 2, 256, 0, stream>>>(x1p, idx, w3h, w3l, wdt3, s3, b3, w4h, w4l, s4, b4, x2p);
    edge_mfma_kernel<0><<<BATCH * N_PTS / 2, 256, 0, stream>>>(x2p, idx, w5h, w5l, wdt5, s5, b5, nullptr, nullptr, nullptr, nullptr, x3p);
    gemm_mfma<0, 8, 2, 192, 1024><<<dim3(128, 8), 256, 0, stream>>>(x1p, x2p, x3p, w6h, w6l, s6, b6, nullptr, gpart);
    greduce_kernel<<<16, 256, 0, stream>>>(gpart, g);
    c7_kernel<<<8, 256, 0, stream>>>(g, W7, c7);
    gemm_mfma_c7<8, 2, 192, 512><<<dim3(128, 4), 256, 0, stream>>>(x1p, x2p, x3p, w7h, w7l, s7, b7, c7, h7p);
    gemm_mfma_t<2, 4, 2, 512, 256><<<dim3(256, 2), 256, 0, stream>>>(h7p, w8h, w8l, s8, b8, nullptr, h8p);
    gemm_mfma<3, 4, 1, 256, 64><<<dim3(256, 1), 256, 0, stream>>>(h8p, nullptr, nullptr, w9h, w9l, nullptr, b9, nullptr, outp);
}

// Round 12
// 455.198 us; speedup vs baseline: 1.0332x; 1.0332x over previous
//
#include <hip/hip_runtime.h>

#define N_PTS 4096
#define KNBR 40
#define BATCH 4

typedef __attribute__((ext_vector_type(8))) short bf16x8;
typedef __attribute__((ext_vector_type(4))) float f32x4;

__device__ __forceinline__ float lrelu(float v) { return v > 0.0f ? v : 0.2f * v; }

__device__ __forceinline__ short bf16_rn(float f) {
    unsigned u = __float_as_uint(f);
    unsigned r = (u + 0x7FFFu + ((u >> 16) & 1u)) >> 16;
    return (short)r;
}
__device__ __forceinline__ float bf16f(short h) {
    return __uint_as_float(((unsigned)(unsigned short)h) << 16);
}
__device__ __forceinline__ unsigned packbf(float v) {
    short h = bf16_rn(v);
    float r = v - bf16f(h);
    short l = bf16_rn(r);
    return (((unsigned)(unsigned short)h) << 16) | (unsigned)(unsigned short)l;
}
// truncate-hi split: hi = trunc(v), lo = trunc(v - hi). err(hi+lo) ~ 2^-16|v|
__device__ __forceinline__ unsigned pack_trunc(float v) {
    unsigned u = __float_as_uint(v);
    unsigned hi = u & 0xFFFF0000u;
    float r = v - __uint_as_float(hi);
    return hi | (__float_as_uint(r) >> 16);
}

// ---------------- KNN: exact top-40 via radix bin select + candidate rank (round-10 best) ----------------
__global__ __launch_bounds__(256) void knn_kernel(const float* __restrict__ x, int* __restrict__ idxo)
{
    const int t = threadIdx.x;
    const int pt = blockIdx.x;
    const int b = pt >> 12, n = pt & 4095;
    const float* xb = x + b * 3 * N_PTS;
    const int lane = t & 63, wv = t >> 6;

    __shared__ unsigned hist[4096];
    __shared__ unsigned wtot[4];
    __shared__ int sh[8];
    unsigned* cov = hist;
    int* cidx = (int*)(hist + 2048);

    const float c0 = xb[n], c1 = xb[N_PTS + n], c2 = xb[2 * N_PTS + n];
    const float cc = c0 * c0 + c1 * c1 + c2 * c2;

    unsigned ov[16];
#pragma unroll
    for (int j = 0; j < 16; ++j) {
        int m = t + j * 256;
        float a0 = xb[m], a1 = xb[N_PTS + m], a2 = xb[2 * N_PTS + m];
        float d = 2.0f * (c0 * a0 + c1 * a1 + c2 * a2) - cc - (a0 * a0 + a1 * a1 + a2 * a2);
        unsigned u = __float_as_uint(d);
        ov[j] = (u & 0x80000000u) ? ~u : (u | 0x80000000u);
    }

#pragma unroll
    for (int j = 0; j < 16; ++j) hist[t + j * 256] = 0;
    if (t < 8) sh[t] = 0;
    __syncthreads();
#pragma unroll
    for (int j = 0; j < 16; ++j) atomicAdd(&hist[ov[j] >> 20], 1u);
    __syncthreads();

    unsigned cs = 0;
    {
        const int rot = (t >> 1) & 15;
#pragma unroll
        for (int q = 0; q < 16; ++q) cs += hist[t * 16 + ((q + rot) & 15)];
    }
    unsigned val = cs;
#pragma unroll
    for (int off = 1; off < 64; off <<= 1) {
        unsigned o = __shfl_down(val, off, 64);
        if (lane + off < 64) val += o;
    }
    if (lane == 0) wtot[wv] = val;
    __syncthreads();
    unsigned above_w = 0;
    for (int q = wv + 1; q < 4; ++q) above_w += wtot[q];
    unsigned Sincl = val + above_w;
    unsigned excl = Sincl - cs;
    if (excl < KNBR && Sincl >= KNBR) { sh[0] = t; sh[1] = (int)excl; }
    __syncthreads();
    if (t == 0) {
        int tstar = sh[0];
        unsigned run = (unsigned)sh[1];
        int B1 = -1; unsigned hcnt = 0;
        for (int q = 15; q >= 0; --q) {
            unsigned h = hist[tstar * 16 + q];
            if (run + h >= KNBR) { B1 = tstar * 16 + q; hcnt = h; break; }
            run += h;
        }
        sh[0] = B1; sh[1] = (int)run;
        int R1 = KNBR - (int)run;
        sh[7] = R1;
        sh[2] = ((int)hcnt > R1) ? 1 : 0;
    }
    __syncthreads();
    const unsigned B1 = (unsigned)sh[0];
    const int needRef = sh[2];
    const int R1 = sh[7];
    const int nab = sh[1];

#pragma unroll
    for (int j = 0; j < 16; ++j) {
        unsigned bb = ov[j] >> 20;
        if (bb > B1) { int p = atomicAdd(&sh[3], 1); idxo[pt * KNBR + p] = t + j * 256; }
        else if (bb == B1) {
            if (!needRef) { int p = atomicAdd(&sh[3], 1); idxo[pt * KNBR + p] = t + j * 256; }
            else { int q = atomicAdd(&sh[6], 1); if (q < 2048) { cov[q] = ov[j]; cidx[q] = t + j * 256; } }
        }
    }
    if (!needRef) return;
    __syncthreads();
    const int C = sh[6] < 2048 ? sh[6] : 2048;
    for (int j = t; j < C; j += 256) {
        unsigned myv = cov[j]; int myi = cidx[j];
        int rank = 0;
        for (int q = 0; q < C; ++q) {
            unsigned v = cov[q];
            rank += (v > myv || (v == myv && cidx[q] < myi)) ? 1 : 0;
        }
        if (rank < R1) idxo[pt * KNBR + nab + rank] = myi;
    }
}

// ---------------- Layer 1 via MFMA: 4 pts/block, M=160 ----------------
__global__ __launch_bounds__(256) void layer1_mfma_kernel(const float* __restrict__ x, const int* __restrict__ idx,
    const float* __restrict__ W1, const float* __restrict__ s1, const float* __restrict__ b1,
    const short* __restrict__ w2h, const short* __restrict__ w2l,
    const float* __restrict__ s2, const float* __restrict__ b2,
    unsigned* __restrict__ x1p)
{
    const int t = threadIdx.x;
    const int pt0 = blockIdx.x * 4;
    const int b = pt0 >> 12;
    const float* xb = x + b * 3 * N_PTS;
    const int lane = t & 63, w = t >> 6;
    const int cn = lane & 15, kg = lane >> 4;

    __shared__ int idxs[160];
    __shared__ float w1t[384];          // [6][64] transposed W1
    __shared__ float ctrv[4][64];
    __shared__ float nbrc[160][4];
    __shared__ __align__(16) short A_hi[160 * 72];
    __shared__ __align__(16) short A_lo[160 * 72];

    if (t < 160) idxs[t] = idx[pt0 * KNBR + t];
    if (t < 64) {
#pragma unroll
        for (int j = 0; j < 6; ++j) w1t[j * 64 + t] = W1[t * 6 + j];
    }
    __syncthreads();
#pragma unroll
    for (int rr = 0; rr < 2; ++rr) {
        int e = rr * 256 + t;
        if (e < 480) { int k = e / 3, j = e % 3; nbrc[k][j] = xb[j * N_PTS + idxs[k]]; }
    }
    {
        int p = t >> 6, o = t & 63;
        int n = (pt0 + p) & 4095;
        float cx = xb[n], cy = xb[N_PTS + n], cz = xb[2 * N_PTS + n];
        ctrv[p][o] = (w1t[192 + o] - w1t[o]) * cx + (w1t[256 + o] - w1t[64 + o]) * cy
                   + (w1t[320 + o] - w1t[128 + o]) * cz;
    }
    bf16x8 bh[2], bl[2];
#pragma unroll
    for (int kc = 0; kc < 2; ++kc) {
        int off = (w * 16 + cn) * 64 + kc * 32 + kg * 8;
        bh[kc] = *(const bf16x8*)(w2h + off);
        bl[kc] = *(const bf16x8*)(w2l + off);
    }
    __syncthreads();
    {
        const int o = t & 63;
        const float w0 = w1t[o], w1v = w1t[64 + o], w2v = w1t[128 + o];
        const float sv = s1[o], bv = b1[o];
        const float cva = ctrv[0][o], cvb = ctrv[1][o], cvc = ctrv[2][o], cvd = ctrv[3][o];
#pragma unroll
        for (int r = 0; r < 40; ++r) {
            int k = (t >> 6) + r * 4;
            float cv = k >= 80 ? (k >= 120 ? cvd : cvc) : (k >= 40 ? cvb : cva);
            float v = w0 * nbrc[k][0] + w1v * nbrc[k][1] + w2v * nbrc[k][2] + cv;
            v = lrelu(v * sv + bv);
            unsigned u = __float_as_uint(v);
            unsigned hi = u & 0xFFFF0000u;
            A_hi[k * 72 + o] = (short)(u >> 16);
            float rr = v - __uint_as_float(hi);
            A_lo[k * 72 + o] = (short)(__float_as_uint(rr) >> 16);
        }
    }
    __syncthreads();
    f32x4 acc[10];
#pragma unroll
    for (int mt = 0; mt < 10; ++mt) {
        f32x4 a = {0.f, 0.f, 0.f, 0.f};
#pragma unroll
        for (int kc = 0; kc < 2; ++kc) {
            int ao = (mt * 16 + cn) * 72 + kc * 32 + kg * 8;
            bf16x8 ah = *(const bf16x8*)(A_hi + ao);
            bf16x8 al = *(const bf16x8*)(A_lo + ao);
            a = __builtin_amdgcn_mfma_f32_16x16x32_bf16(al, bh[kc], a, 0, 0, 0);
            a = __builtin_amdgcn_mfma_f32_16x16x32_bf16(ah, bl[kc], a, 0, 0, 0);
            a = __builtin_amdgcn_mfma_f32_16x16x32_bf16(ah, bh[kc], a, 0, 0, 0);
        }
        acc[mt] = a;
    }
    const int o1 = w * 16 + cn;
    const float sB = s2[o1], bB = b2[o1];
    float m0 = -1e30f, m1 = -1e30f, m2 = -1e30f, m3 = -1e30f;
#pragma unroll
    for (int mt = 0; mt < 10; ++mt)
#pragma unroll
        for (int reg = 0; reg < 4; ++reg) {
            int row = mt * 16 + kg * 4 + reg;
            float v = lrelu(acc[mt][reg] * sB + bB);
            if (row < 40) m0 = fmaxf(m0, v);
            else if (row < 80) m1 = fmaxf(m1, v);
            else if (row < 120) m2 = fmaxf(m2, v);
            else m3 = fmaxf(m3, v);
        }
    m0 = fmaxf(m0, __shfl_xor(m0, 16, 64)); m0 = fmaxf(m0, __shfl_xor(m0, 32, 64));
    m1 = fmaxf(m1, __shfl_xor(m1, 16, 64)); m1 = fmaxf(m1, __shfl_xor(m1, 32, 64));
    m2 = fmaxf(m2, __shfl_xor(m2, 16, 64)); m2 = fmaxf(m2, __shfl_xor(m2, 32, 64));
    m3 = fmaxf(m3, __shfl_xor(m3, 16, 64)); m3 = fmaxf(m3, __shfl_xor(m3, 32, 64));
    if (kg == 0) {
        x1p[pt0 * 64 + o1] = packbf(m0);
        x1p[(pt0 + 1) * 64 + o1] = packbf(m1);
        x1p[(pt0 + 2) * 64 + o1] = packbf(m2);
        x1p[(pt0 + 3) * 64 + o1] = packbf(m3);
    }
}

// ---------------- prep: edge-conv + W2 weights -> bf16 hi/lo + ctr-weight transpose ----------------
__global__ __launch_bounds__(256) void prep_kernel(const float* __restrict__ W2, const float* __restrict__ W3,
    const float* __restrict__ W4, const float* __restrict__ W5,
    short* __restrict__ w2h, short* __restrict__ w2l,
    short* __restrict__ w3h, short* __restrict__ w3l,
    short* __restrict__ w4h, short* __restrict__ w4l,
    short* __restrict__ w5h, short* __restrict__ w5l,
    float* __restrict__ wdt3, float* __restrict__ wdt5)
{
    int e = blockIdx.x * 256 + threadIdx.x;   // 4096
    int o = e >> 6, i = e & 63;
    float a = W3[o * 128 + i];
    short h = bf16_rn(a);
    w3h[e] = h; w3l[e] = bf16_rn(a - bf16f(h));
    wdt3[i * 64 + o] = W3[o * 128 + 64 + i] - a;
    float c = W4[o * 64 + i];
    h = bf16_rn(c);
    w4h[e] = h; w4l[e] = bf16_rn(c - bf16f(h));
    float d = W5[o * 128 + i];
    h = bf16_rn(d);
    w5h[e] = h; w5l[e] = bf16_rn(d - bf16f(h));
    wdt5[i * 64 + o] = W5[o * 128 + 64 + i] - d;
    float e2 = W2[o * 64 + i];
    h = bf16_rn(e2);
    w2h[e] = h; w2l[e] = bf16_rn(e2 - bf16f(h));
}

// ---------------- prep2: W6/W7(slice)/W8/W9 -> split bf16 hi/lo ----------------
__global__ __launch_bounds__(256) void prep2_kernel(const float* __restrict__ W6, const float* __restrict__ W7,
    const float* __restrict__ W8, const float* __restrict__ W9,
    short* __restrict__ w6h, short* __restrict__ w6l,
    short* __restrict__ w7h, short* __restrict__ w7l,
    short* __restrict__ w8h, short* __restrict__ w8l,
    short* __restrict__ w9h, short* __restrict__ w9l)
{
    int e = blockIdx.x * 256 + threadIdx.x;
    float v; short* dh; short* dl; int di;
    if (e < 196608) {
        v = W6[e]; dh = w6h; dl = w6l; di = e;
    } else if (e < 294912) {
        int ee = e - 196608;
        int o = ee / 192, k = ee - o * 192;
        v = W7[o * 1216 + 1024 + k]; dh = w7h; dl = w7l; di = ee;
    } else if (e < 425984) {
        int ee = e - 294912;
        v = W8[ee]; dh = w8h; dl = w8l; di = ee;
    } else if (e < 442368) {
        int ee = e - 425984;
        int o = ee >> 8, k = ee & 255;
        v = (o < 63) ? W9[o * 256 + k] : 0.0f;
        dh = w9h; dl = w9l; di = ee;
    } else return;
    short h = bf16_rn(v);
    dh[di] = h; dl[di] = bf16_rn(v - bf16f(h));
}

// ---------------- Edge layers via MFMA (split-bf16), packed input, 4 points/block, M=160 --------
template<int HAS2>
__global__ __launch_bounds__(256) void edge_mfma_kernel(const unsigned* __restrict__ srcp, const int* __restrict__ idx,
    const short* __restrict__ wah, const short* __restrict__ wal, const float* __restrict__ wdt,
    const float* __restrict__ sa, const float* __restrict__ ba,
    const short* __restrict__ wbh, const short* __restrict__ wbl,
    const float* __restrict__ sb, const float* __restrict__ bb,
    unsigned* __restrict__ xpout)
{
    const int t = threadIdx.x;
    const int pt0 = blockIdx.x * 4;
    const int b = pt0 >> 12;
    const int lane = t & 63, w = t >> 6;
    const int cn = lane & 15, kg = lane >> 4;

    __shared__ int idxs[160];
    __shared__ float ctr1[4][64];
    __shared__ float ctrv[4][64];
    __shared__ __align__(16) short A_hi[160 * 72];
    __shared__ __align__(16) short A_lo[160 * 72];

    if (t < 160) idxs[t] = idx[pt0 * KNBR + t];
    {
        int p = t >> 6, i = t & 63;
        unsigned u = srcp[(pt0 + p) * 64 + i];
        ctr1[p][i] = bf16f((short)(u >> 16)) + bf16f((short)u);
    }
    __syncthreads();

    bf16x8 bh[2], bl[2];
#pragma unroll
    for (int kc = 0; kc < 2; ++kc) {
        int off = (w * 16 + cn) * 64 + kc * 32 + kg * 8;
        bh[kc] = *(const bf16x8*)(wah + off);
        bl[kc] = *(const bf16x8*)(wal + off);
    }

    // gather packed neighbors -> unpack to hi/lo LDS planes (2 shifts/elem)
    {
        const int r0 = t >> 4, c4 = (t & 15) * 4;
#pragma unroll
        for (int r = 0; r < 10; ++r) {
            int row = r * 16 + r0;
            uint4 v = *(const uint4*)(srcp + (size_t)(b * N_PTS + idxs[row]) * 64 + c4);
            short4 h, l;
            h.x = (short)(v.x >> 16); l.x = (short)v.x;
            h.y = (short)(v.y >> 16); l.y = (short)v.y;
            h.z = (short)(v.z >> 16); l.z = (short)v.z;
            h.w = (short)(v.w >> 16); l.w = (short)v.w;
            *(short4*)(A_hi + row * 72 + c4) = h;
            *(short4*)(A_lo + row * 72 + c4) = l;
        }
    }
    // ctrv: each thread does the full 64-FMA dot for its (p,o)
    {
        int p = t >> 6, o = t & 63;
        float s = 0.0f;
#pragma unroll 8
        for (int i = 0; i < 64; ++i) s = fmaf(wdt[i * 64 + o], ctr1[p][i], s);
        ctrv[p][o] = s;
    }
    __syncthreads();

    f32x4 acc[10];
#pragma unroll
    for (int mt = 0; mt < 10; ++mt) {
        f32x4 a = {0.f, 0.f, 0.f, 0.f};
#pragma unroll
        for (int kc = 0; kc < 2; ++kc) {
            int ao = (mt * 16 + cn) * 72 + kc * 32 + kg * 8;
            bf16x8 ah = *(const bf16x8*)(A_hi + ao);
            bf16x8 al = *(const bf16x8*)(A_lo + ao);
            a = __builtin_amdgcn_mfma_f32_16x16x32_bf16(al, bh[kc], a, 0, 0, 0);
            a = __builtin_amdgcn_mfma_f32_16x16x32_bf16(ah, bl[kc], a, 0, 0, 0);
            a = __builtin_amdgcn_mfma_f32_16x16x32_bf16(ah, bh[kc], a, 0, 0, 0);
        }
        acc[mt] = a;
    }

    const int o1 = w * 16 + cn;
    const float cva = ctrv[0][o1], cvb = ctrv[1][o1], cvc = ctrv[2][o1], cvd = ctrv[3][o1];
    const float sA = sa[o1], bA = ba[o1];

    if (HAS2) {
        __syncthreads();   // all MFMA reads of A done before overwrite
#pragma unroll
        for (int mt = 0; mt < 10; ++mt) {
#pragma unroll
            for (int reg = 0; reg < 4; ++reg) {
                int row = mt * 16 + kg * 4 + reg;
                float cv = row >= 80 ? (row >= 120 ? cvd : cvc) : (row >= 40 ? cvb : cva);
                float v = lrelu((acc[mt][reg] + cv) * sA + bA);
                unsigned u = __float_as_uint(v);
                unsigned hi = u & 0xFFFF0000u;
                A_hi[row * 72 + o1] = (short)(u >> 16);
                float rr = v - __uint_as_float(hi);
                A_lo[row * 72 + o1] = (short)(__float_as_uint(rr) >> 16);
            }
        }
        __syncthreads();
#pragma unroll
        for (int kc = 0; kc < 2; ++kc) {
            int off = (w * 16 + cn) * 64 + kc * 32 + kg * 8;
            bh[kc] = *(const bf16x8*)(wbh + off);
            bl[kc] = *(const bf16x8*)(wbl + off);
        }
#pragma unroll
        for (int mt = 0; mt < 10; ++mt) {
            f32x4 a = {0.f, 0.f, 0.f, 0.f};
#pragma unroll
            for (int kc = 0; kc < 2; ++kc) {
                int ao = (mt * 16 + cn) * 72 + kc * 32 + kg * 8;
                bf16x8 ah = *(const bf16x8*)(A_hi + ao);
                bf16x8 al = *(const bf16x8*)(A_lo + ao);
                a = __builtin_amdgcn_mfma_f32_16x16x32_bf16(al, bh[kc], a, 0, 0, 0);
                a = __builtin_amdgcn_mfma_f32_16x16x32_bf16(ah, bl[kc], a, 0, 0, 0);
                a = __builtin_amdgcn_mfma_f32_16x16x32_bf16(ah, bh[kc], a, 0, 0, 0);
            }
            acc[mt] = a;
        }
        const float sB = sb[o1], bB = bb[o1];
        float m0 = -1e30f, m1 = -1e30f, m2 = -1e30f, m3 = -1e30f;
#pragma unroll
        for (int mt = 0; mt < 10; ++mt)
#pragma unroll
            for (int reg = 0; reg < 4; ++reg) {
                int row = mt * 16 + kg * 4 + reg;
                float v = lrelu(acc[mt][reg] * sB + bB);
                if (row < 40) m0 = fmaxf(m0, v);
                else if (row < 80) m1 = fmaxf(m1, v);
                else if (row < 120) m2 = fmaxf(m2, v);
                else m3 = fmaxf(m3, v);
            }
        m0 = fmaxf(m0, __shfl_xor(m0, 16, 64)); m0 = fmaxf(m0, __shfl_xor(m0, 32, 64));
        m1 = fmaxf(m1, __shfl_xor(m1, 16, 64)); m1 = fmaxf(m1, __shfl_xor(m1, 32, 64));
        m2 = fmaxf(m2, __shfl_xor(m2, 16, 64)); m2 = fmaxf(m2, __shfl_xor(m2, 32, 64));
        m3 = fmaxf(m3, __shfl_xor(m3, 16, 64)); m3 = fmaxf(m3, __shfl_xor(m3, 32, 64));
        if (kg == 0) {
            xpout[pt0 * 64 + o1] = packbf(m0);
            xpout[(pt0 + 1) * 64 + o1] = packbf(m1);
            xpout[(pt0 + 2) * 64 + o1] = packbf(m2);
            xpout[(pt0 + 3) * 64 + o1] = packbf(m3);
        }
    } else {
        float m0 = -1e30f, m1 = -1e30f, m2 = -1e30f, m3 = -1e30f;
#pragma unroll
        for (int mt = 0; mt < 10; ++mt)
#pragma unroll
            for (int reg = 0; reg < 4; ++reg) {
                int row = mt * 16 + kg * 4 + reg;
                float cv = row >= 80 ? (row >= 120 ? cvd : cvc) : (row >= 40 ? cvb : cva);
                float v = lrelu((acc[mt][reg] + cv) * sA + bA);
                if (row < 40) m0 = fmaxf(m0, v);
                else if (row < 80) m1 = fmaxf(m1, v);
                else if (row < 120) m2 = fmaxf(m2, v);
                else m3 = fmaxf(m3, v);
            }
        m0 = fmaxf(m0, __shfl_xor(m0, 16, 64)); m0 = fmaxf(m0, __shfl_xor(m0, 32, 64));
        m1 = fmaxf(m1, __shfl_xor(m1, 16, 64)); m1 = fmaxf(m1, __shfl_xor(m1, 32, 64));
        m2 = fmaxf(m2, __shfl_xor(m2, 16, 64)); m2 = fmaxf(m2, __shfl_xor(m2, 32, 64));
        m3 = fmaxf(m3, __shfl_xor(m3, 16, 64)); m3 = fmaxf(m3, __shfl_xor(m3, 32, 64));
        if (kg == 0) {
            xpout[pt0 * 64 + o1] = packbf(m0);
            xpout[(pt0 + 1) * 64 + o1] = packbf(m1);
            xpout[(pt0 + 2) * 64 + o1] = packbf(m2);
            xpout[(pt0 + 3) * 64 + o1] = packbf(m3);
        }
    }
}

// ---------------- Split-bf16 MFMA GEMM, fused epilogues ----------------
// MODE 0: conv6 (A=x123p K=192, lrelu, per-block col-max -> gpart)
// MODE 3: conv9 (A=h8p K=256, +b9, transposed fp32 store, col<63)
template<int MODE, int MT, int NT, int KD, int NTOT>
__global__ __launch_bounds__(256) void gemm_mfma(
    const unsigned* __restrict__ A0, const unsigned* __restrict__ A1, const unsigned* __restrict__ A2,
    const short* __restrict__ Bh, const short* __restrict__ Bl,
    const float* __restrict__ sv, const float* __restrict__ bvv,
    const float* __restrict__ extra, void* __restrict__ outp)
{
    const int t = threadIdx.x;
    const int w = t >> 6, lane = t & 63;
    const int cn = lane & 15, kg = lane >> 4;
    const int m0 = blockIdx.x * (MT * 16);
    const int n0 = blockIdx.y * (NT * 64);

    __shared__ __align__(16) short Abuf2[2 * MT * 16 * 40];
    short* A_hi = Abuf2;
    short* A_lo = Abuf2 + MT * 16 * 40;

    f32x4 acc[MT][NT];
#pragma unroll
    for (int mt = 0; mt < MT; ++mt)
#pragma unroll
        for (int nt = 0; nt < NT; ++nt) acc[mt][nt] = (f32x4){0.f, 0.f, 0.f, 0.f};

    for (int kc = 0; kc < KD / 32; ++kc) {
        {
            const int kq = (t & 7) * 4;
            const int r0 = t >> 3;
#pragma unroll
            for (int rr = 0; rr < (MT * 16) / 32; ++rr) {
                int row = r0 + rr * 32;
                int gk = kc * 32 + kq;
                uint4 v;
                if (MODE == 0) {
                    const unsigned* srcp = (gk < 64) ? A0 : ((gk < 128) ? A1 : A2);
                    v = *(const uint4*)(srcp + (size_t)(m0 + row) * 64 + (gk & 63));
                } else {
                    v = *(const uint4*)(A0 + (size_t)(m0 + row) * KD + gk);
                }
                short4 h, l;
                h.x = (short)(v.x >> 16); l.x = (short)v.x;
                h.y = (short)(v.y >> 16); l.y = (short)v.y;
                h.z = (short)(v.z >> 16); l.z = (short)v.z;
                h.w = (short)(v.w >> 16); l.w = (short)v.w;
                *(short4*)(A_hi + row * 40 + kq) = h;
                *(short4*)(A_lo + row * 40 + kq) = l;
            }
        }
        __syncthreads();
        bf16x8 bh[NT], bl[NT];
#pragma unroll
        for (int nt = 0; nt < NT; ++nt) {
            int col = n0 + (w * NT + nt) * 16 + cn;
            int boff = col * KD + kc * 32 + kg * 8;
            bh[nt] = *(const bf16x8*)(Bh + boff);
            bl[nt] = *(const bf16x8*)(Bl + boff);
        }
#pragma unroll
        for (int mt = 0; mt < MT; ++mt) {
            int ao = (mt * 16 + cn) * 40 + kg * 8;
            bf16x8 ah = *(const bf16x8*)(A_hi + ao);
            bf16x8 al = *(const bf16x8*)(A_lo + ao);
#pragma unroll
            for (int nt = 0; nt < NT; ++nt) {
                acc[mt][nt] = __builtin_amdgcn_mfma_f32_16x16x32_bf16(al, bh[nt], acc[mt][nt], 0, 0, 0);
                acc[mt][nt] = __builtin_amdgcn_mfma_f32_16x16x32_bf16(ah, bl[nt], acc[mt][nt], 0, 0, 0);
                acc[mt][nt] = __builtin_amdgcn_mfma_f32_16x16x32_bf16(ah, bh[nt], acc[mt][nt], 0, 0, 0);
            }
        }
        __syncthreads();
    }

    if (MODE == 0) {
        float* gp = (float*)outp;
#pragma unroll
        for (int nt = 0; nt < NT; ++nt) {
            int col = n0 + (w * NT + nt) * 16 + cn;
            float s = sv[col], bb = bvv[col];
            float mx = -1e30f;
#pragma unroll
            for (int mt = 0; mt < MT; ++mt)
#pragma unroll
                for (int r = 0; r < 4; ++r) mx = fmaxf(mx, lrelu(acc[mt][nt][r] * s + bb));
            mx = fmaxf(mx, __shfl_xor(mx, 16, 64));
            mx = fmaxf(mx, __shfl_xor(mx, 32, 64));
            if (kg == 0) gp[blockIdx.x * NTOT + col] = mx;
        }
    } else {
        float* of = (float*)outp;
        const int b = m0 >> 12;
        const int nrow0 = m0 & 4095;
        int col = w * 16 + cn;
        if (col < 63) {
            float bb = bvv[col];
#pragma unroll
            for (int mt = 0; mt < MT; ++mt) {
                float4 o4;
                o4.x = acc[mt][0][0] + bb; o4.y = acc[mt][0][1] + bb;
                o4.z = acc[mt][0][2] + bb; o4.w = acc[mt][0][3] + bb;
                *(float4*)(of + (size_t)(b * 63 + col) * N_PTS + nrow0 + mt * 16 + kg * 4) = o4;
            }
        }
    }
}

// ---------------- MODE 2-style GEMM (contiguous packed A), packed output via LDS transpose ----------------
template<int MODE, int MT, int NT, int KD, int NTOT>
__global__ __launch_bounds__(256) void gemm_mfma_t(
    const unsigned* __restrict__ A0,
    const short* __restrict__ Bh, const short* __restrict__ Bl,
    const float* __restrict__ sv, const float* __restrict__ bvv,
    const float* __restrict__ extra, unsigned* __restrict__ op)
{
    const int t = threadIdx.x;
    const int w = t >> 6, lane = t & 63;
    const int cn = lane & 15, kg = lane >> 4;
    const int m0 = blockIdx.x * (MT * 16);
    const int n0 = blockIdx.y * (NT * 64);

    __shared__ __align__(16) short Abuf2[2 * MT * 16 * 40 > 2 * 16 * 132 * 2 ? 2 * MT * 16 * 40 : 2 * 16 * 132 * 2];
    short* A_hi = Abuf2;
    short* A_lo = Abuf2 + MT * 16 * 40;

    f32x4 acc[MT][NT];
#pragma unroll
    for (int mt = 0; mt < MT; ++mt)
#pragma unroll
        for (int nt = 0; nt < NT; ++nt) acc[mt][nt] = (f32x4){0.f, 0.f, 0.f, 0.f};

    for (int kc = 0; kc < KD / 32; ++kc) {
        {
            const int kq = (t & 7) * 4;
            const int r0 = t >> 3;
#pragma unroll
            for (int rr = 0; rr < (MT * 16) / 32; ++rr) {
                int row = r0 + rr * 32;
                int gk = kc * 32 + kq;
                uint4 v = *(const uint4*)(A0 + (size_t)(m0 + row) * KD + gk);
                short4 h, l;
                h.x = (short)(v.x >> 16); l.x = (short)v.x;
                h.y = (short)(v.y >> 16); l.y = (short)v.y;
                h.z = (short)(v.z >> 16); l.z = (short)v.z;
                h.w = (short)(v.w >> 16); l.w = (short)v.w;
                *(short4*)(A_hi + row * 40 + kq) = h;
                *(short4*)(A_lo + row * 40 + kq) = l;
            }
        }
        __syncthreads();
        bf16x8 bh[NT], bl[NT];
#pragma unroll
        for (int nt = 0; nt < NT; ++nt) {
            int col = n0 + (w * NT + nt) * 16 + cn;
            int boff = col * KD + kc * 32 + kg * 8;
            bh[nt] = *(const bf16x8*)(Bh + boff);
            bl[nt] = *(const bf16x8*)(Bl + boff);
        }
#pragma unroll
        for (int mt = 0; mt < MT; ++mt) {
            int ao = (mt * 16 + cn) * 40 + kg * 8;
            bf16x8 ah = *(const bf16x8*)(A_hi + ao);
            bf16x8 al = *(const bf16x8*)(A_lo + ao);
#pragma unroll
            for (int nt = 0; nt < NT; ++nt) {
                acc[mt][nt] = __builtin_amdgcn_mfma_f32_16x16x32_bf16(al, bh[nt], acc[mt][nt], 0, 0, 0);
                acc[mt][nt] = __builtin_amdgcn_mfma_f32_16x16x32_bf16(ah, bl[nt], acc[mt][nt], 0, 0, 0);
                acc[mt][nt] = __builtin_amdgcn_mfma_f32_16x16x32_bf16(ah, bh[nt], acc[mt][nt], 0, 0, 0);
            }
        }
        __syncthreads();
    }

    unsigned* T = (unsigned*)Abuf2;
    const int b = m0 >> 12;
#pragma unroll
    for (int mt = 0; mt < MT; ++mt) {
#pragma unroll
        for (int nt = 0; nt < NT; ++nt) {
            int col = n0 + (w * NT + nt) * 16 + cn;
            float s = sv[col], bb = bvv[col];
            float cc = (MODE == 1) ? extra[b * 512 + col] : 0.0f;
#pragma unroll
            for (int r = 0; r < 4; ++r) {
                float v = lrelu((acc[mt][nt][r] + cc) * s + bb);
                T[(kg * 4 + r) * 132 + (w * NT + nt) * 16 + cn] = pack_trunc(v);
            }
        }
        __syncthreads();
        {
            int row = t >> 4, c0 = (t & 15) * 8;
            uint4 u0 = *(uint4*)(T + row * 132 + c0);
            uint4 u1 = *(uint4*)(T + row * 132 + c0 + 4);
            int grow = m0 + mt * 16 + row;
            *(uint4*)(op + (size_t)grow * NTOT + n0 + c0) = u0;
            *(uint4*)(op + (size_t)grow * NTOT + n0 + c0 + 4) = u1;
        }
        __syncthreads();
    }
}

// ---------------- MODE 1 GEMM (three packed x-arrays), +c7 epilogue, packed output ----------------
template<int MT, int NT, int KD, int NTOT>
__global__ __launch_bounds__(256) void gemm_mfma_c7(
    const unsigned* __restrict__ A0, const unsigned* __restrict__ A1, const unsigned* __restrict__ A2,
    const short* __restrict__ Bh, const short* __restrict__ Bl,
    const float* __restrict__ sv, const float* __restrict__ bvv,
    const float* __restrict__ extra, unsigned* __restrict__ op)
{
    const int t = threadIdx.x;
    const int w = t >> 6, lane = t & 63;
    const int cn = lane & 15, kg = lane >> 4;
    const int m0 = blockIdx.x * (MT * 16);
    const int n0 = blockIdx.y * (NT * 64);

    __shared__ __align__(16) short Abuf2[2 * MT * 16 * 40 > 2 * 16 * 132 * 2 ? 2 * MT * 16 * 40 : 2 * 16 * 132 * 2];
    short* A_hi = Abuf2;
    short* A_lo = Abuf2 + MT * 16 * 40;

    f32x4 acc[MT][NT];
#pragma unroll
    for (int mt = 0; mt < MT; ++mt)
#pragma unroll
        for (int nt = 0; nt < NT; ++nt) acc[mt][nt] = (f32x4){0.f, 0.f, 0.f, 0.f};

    for (int kc = 0; kc < KD / 32; ++kc) {
        {
            const int kq = (t & 7) * 4;
            const int r0 = t >> 3;
#pragma unroll
            for (int rr = 0; rr < (MT * 16) / 32; ++rr) {
                int row = r0 + rr * 32;
                int gk = kc * 32 + kq;
                const unsigned* srcp = (gk < 64) ? A0 : ((gk < 128) ? A1 : A2);
                uint4 v = *(const uint4*)(srcp + (size_t)(m0 + row) * 64 + (gk & 63));
                short4 h, l;
                h.x = (short)(v.x >> 16); l.x = (short)v.x;
                h.y = (short)(v.y >> 16); l.y = (short)v.y;
                h.z = (short)(v.z >> 16); l.z = (short)v.z;
                h.w = (short)(v.w >> 16); l.w = (short)v.w;
                *(short4*)(A_hi + row * 40 + kq) = h;
                *(short4*)(A_lo + row * 40 + kq) = l;
            }
        }
        __syncthreads();
        bf16x8 bh[NT], bl[NT];
#pragma unroll
        for (int nt = 0; nt < NT; ++nt) {
            int col = n0 + (w * NT + nt) * 16 + cn;
            int boff = col * KD + kc * 32 + kg * 8;
            bh[nt] = *(const bf16x8*)(Bh + boff);
            bl[nt] = *(const bf16x8*)(Bl + boff);
        }
#pragma unroll
        for (int mt = 0; mt < MT; ++mt) {
            int ao = (mt * 16 + cn) * 40 + kg * 8;
            bf16x8 ah = *(const bf16x8*)(A_hi + ao);
            bf16x8 al = *(const bf16x8*)(A_lo + ao);
#pragma unroll
            for (int nt = 0; nt < NT; ++nt) {
                acc[mt][nt] = __builtin_amdgcn_mfma_f32_16x16x32_bf16(al, bh[nt], acc[mt][nt], 0, 0, 0);
                acc[mt][nt] = __builtin_amdgcn_mfma_f32_16x16x32_bf16(ah, bl[nt], acc[mt][nt], 0, 0, 0);
                acc[mt][nt] = __builtin_amdgcn_mfma_f32_16x16x32_bf16(ah, bh[nt], acc[mt][nt], 0, 0, 0);
            }
        }
        __syncthreads();
    }

    unsigned* T = (unsigned*)Abuf2;
    const int b = m0 >> 12;
#pragma unroll
    for (int mt = 0; mt < MT; ++mt) {
#pragma unroll
        for (int nt = 0; nt < NT; ++nt) {
            int col = n0 + (w * NT + nt) * 16 + cn;
            float s = sv[col], bb = bvv[col];
            float cc = extra[b * 512 + col];
#pragma unroll
            for (int r = 0; r < 4; ++r) {
                float v = lrelu((acc[mt][nt][r] + cc) * s + bb);
                T[(kg * 4 + r) * 132 + (w * NT + nt) * 16 + cn] = pack_trunc(v);
            }
        }
        __syncthreads();
        {
            int row = t >> 4, c0 = (t & 15) * 8;
            uint4 u0 = *(uint4*)(T + row * 132 + c0);
            uint4 u1 = *(uint4*)(T + row * 132 + c0 + 4);
            int grow = m0 + mt * 16 + row;
            *(uint4*)(op + (size_t)grow * NTOT + n0 + c0) = u0;
            *(uint4*)(op + (size_t)grow * NTOT + n0 + c0 + 4) = u1;
        }
        __syncthreads();
    }
}

__global__ __launch_bounds__(256) void greduce_kernel(const float* __restrict__ gpart, float* __restrict__ g)
{
    int tid = blockIdx.x * 256 + threadIdx.x;   // 4096
    int b = tid >> 10, o = tid & 1023;
    float m = -1e30f;
    for (int q = 0; q < 32; ++q) m = fmaxf(m, gpart[(b * 32 + q) * 1024 + o]);
    g[tid] = m;
}

__global__ __launch_bounds__(256) void c7_kernel(const float* __restrict__ g, const float* __restrict__ W7,
                                                 float* __restrict__ c7)
{
    int tid = blockIdx.x * 256 + threadIdx.x;   // 2048
    int b = tid >> 9, o = tid & 511;
    const float* gb = g + b * 1024;
    const float* wr = W7 + o * 1216;
    float s = 0.0f;
    for (int i = 0; i < 1024; i += 4) {
        float4 wv4 = *reinterpret_cast<const float4*>(&wr[i]);
        float4 gv4 = *reinterpret_cast<const float4*>(&gb[i]);
        s += wv4.x * gv4.x + wv4.y * gv4.y + wv4.z * gv4.z + wv4.w * gv4.w;
    }
    c7[tid] = s;
}

extern "C" void kernel_launch(void* const* d_in, const int* in_sizes, int n_in,
                              void* d_out, int out_size, void* d_ws, size_t ws_size,
                              hipStream_t stream)
{
    const float* x  = (const float*)d_in[0];
    const float* W1 = (const float*)d_in[1];
    const float* s1 = (const float*)d_in[2];
    const float* b1 = (const float*)d_in[3];
    const float* W2 = (const float*)d_in[4];
    const float* s2 = (const float*)d_in[5];
    const float* b2 = (const float*)d_in[6];
    const float* W3 = (const float*)d_in[7];
    const float* s3 = (const float*)d_in[8];
    const float* b3 = (const float*)d_in[9];
    const float* W4 = (const float*)d_in[10];
    const float* s4 = (const float*)d_in[11];
    const float* b4 = (const float*)d_in[12];
    const float* W5 = (const float*)d_in[13];
    const float* s5 = (const float*)d_in[14];
    const float* b5 = (const float*)d_in[15];
    const float* W6 = (const float*)d_in[16];
    const float* s6 = (const float*)d_in[17];
    const float* b6 = (const float*)d_in[18];
    const float* W7 = (const float*)d_in[19];
    const float* s7 = (const float*)d_in[20];
    const float* b7 = (const float*)d_in[21];
    const float* W8 = (const float*)d_in[22];
    const float* s8 = (const float*)d_in[23];
    const float* b8 = (const float*)d_in[24];
    const float* W9 = (const float*)d_in[25];
    const float* b9 = (const float*)d_in[26];

    char* ws = (char*)d_ws;
    int*      idx   = (int*)(ws);                      // 2.62 MB
    unsigned* x1p   = (unsigned*)(ws + 15204352);
    unsigned* x2p   = (unsigned*)(ws + 19398656);
    unsigned* x3p   = (unsigned*)(ws + 23592960);
    float*    gpart = (float*)(ws + 27787264);
    float*    g     = (float*)(ws + 28311552);
    float*    c7    = (float*)(ws + 28327936);
    short*    w3h   = (short*)(ws + 28336128);
    short*    w3l   = w3h + 4096;
    short*    w4h   = w3h + 8192;
    short*    w4l   = w3h + 12288;
    short*    w5h   = w3h + 16384;
    short*    w5l   = w3h + 20480;
    float*    wdt3  = (float*)(ws + 28385280);
    float*    wdt5  = (float*)(ws + 28401664);
    short*    w6h   = (short*)(ws + 28418048);
    short*    w6l   = (short*)(ws + 28811264);
    short*    w7h   = (short*)(ws + 29204480);
    short*    w7l   = (short*)(ws + 29401088);
    short*    w8h   = (short*)(ws + 29597696);
    short*    w8l   = (short*)(ws + 29859840);
    short*    w9h   = (short*)(ws + 30121984);
    short*    w9l   = (short*)(ws + 30154752);
    short*    w2h   = (short*)(ws + 30187520);
    short*    w2l   = (short*)(ws + 30195712);
    unsigned* h7p   = (unsigned*)(ws + 30408704);      // 33.55 MB -> ends 63963136
    unsigned* h8p   = (unsigned*)(ws);                 // aliases dead early buffers
    float*    outp  = (float*)d_out;

    knn_kernel<<<BATCH * N_PTS, 256, 0, stream>>>(x, idx);
    prep_kernel<<<16, 256, 0, stream>>>(W2, W3, W4, W5, w2h, w2l, w3h, w3l, w4h, w4l, w5h, w5l, wdt3, wdt5);
    prep2_kernel<<<1728, 256, 0, stream>>>(W6, W7, W8, W9, w6h, w6l, w7h, w7l, w8h, w8l, w9h, w9l);
    layer1_mfma_kernel<<<BATCH * N_PTS / 4, 256, 0, stream>>>(x, idx, W1, s1, b1, w2h, w2l, s2, b2, x1p);
    edge_mfma_kernel<1><<<BATCH * N_PTS / 4, 256, 0, stream>>>(x1p, idx, w3h, w3l, wdt3, s3, b3, w4h, w4l, s4, b4, x2p);
    edge_mfma_kernel<0><<<BATCH * N_PTS / 4, 256, 0, stream>>>(x2p, idx, w5h, w5l, wdt5, s5, b5, nullptr, nullptr, nullptr, nullptr, x3p);
    gemm_mfma<0, 8, 2, 192, 1024><<<dim3(128, 8), 256, 0, stream>>>(x1p, x2p, x3p, w6h, w6l, s6, b6, nullptr, gpart);
    greduce_kernel<<<16, 256, 0, stream>>>(gpart, g);
    c7_kernel<<<8, 256, 0, stream>>>(g, W7, c7);
    gemm_mfma_c7<8, 2, 192, 512><<<dim3(128, 4), 256, 0, stream>>>(x1p, x2p, x3p, w7h, w7l, s7, b7, c7, h7p);
    gemm_mfma_t<2, 4, 2, 512, 256><<<dim3(256, 2), 256, 0, stream>>>(h7p, w8h, w8l, s8, b8, nullptr, h8p);
    gemm_mfma<3, 4, 1, 256, 64><<<dim3(256, 1), 256, 0, stream>>>(h8p, nullptr, nullptr, w9h, w9l, nullptr, b9, nullptr, outp);
}

// Round 13
// 437.000 us; speedup vs baseline: 1.0762x; 1.0416x over previous
//
#include <hip/hip_runtime.h>

#define N_PTS 4096
#define KNBR 40
#define BATCH 4

typedef __attribute__((ext_vector_type(8))) short bf16x8;
typedef __attribute__((ext_vector_type(4))) float f32x4;

__device__ __forceinline__ float lrelu(float v) { return v > 0.0f ? v : 0.2f * v; }

__device__ __forceinline__ short bf16_rn(float f) {
    unsigned u = __float_as_uint(f);
    unsigned r = (u + 0x7FFFu + ((u >> 16) & 1u)) >> 16;
    return (short)r;
}
__device__ __forceinline__ float bf16f(short h) {
    return __uint_as_float(((unsigned)(unsigned short)h) << 16);
}
__device__ __forceinline__ unsigned packbf(float v) {
    short h = bf16_rn(v);
    float r = v - bf16f(h);
    short l = bf16_rn(r);
    return (((unsigned)(unsigned short)h) << 16) | (unsigned)(unsigned short)l;
}
// truncate-hi split: hi = trunc(v), lo = trunc(v - hi). err(hi+lo) ~ 2^-16|v|
__device__ __forceinline__ unsigned pack_trunc(float v) {
    unsigned u = __float_as_uint(v);
    unsigned hi = u & 0xFFFF0000u;
    float r = v - __uint_as_float(hi);
    return hi | (__float_as_uint(r) >> 16);
}

// ---------------- KNN: exact top-40 via radix bin select + candidate rank ----------------
__global__ __launch_bounds__(256) void knn_kernel(const float* __restrict__ x, int* __restrict__ idxo)
{
    const int t = threadIdx.x;
    const int pt = blockIdx.x;
    const int b = pt >> 12, n = pt & 4095;
    const float* xb = x + b * 3 * N_PTS;
    const int lane = t & 63, wv = t >> 6;

    __shared__ unsigned hist[4096];
    __shared__ unsigned wtot[4];
    __shared__ int sh[8];
    unsigned* cov = hist;
    int* cidx = (int*)(hist + 2048);

    const float c0 = xb[n], c1 = xb[N_PTS + n], c2 = xb[2 * N_PTS + n];
    const float cc = c0 * c0 + c1 * c1 + c2 * c2;

    unsigned ov[16];
#pragma unroll
    for (int j = 0; j < 16; ++j) {
        int m = t + j * 256;
        float a0 = xb[m], a1 = xb[N_PTS + m], a2 = xb[2 * N_PTS + m];
        float d = 2.0f * (c0 * a0 + c1 * a1 + c2 * a2) - cc - (a0 * a0 + a1 * a1 + a2 * a2);
        unsigned u = __float_as_uint(d);
        ov[j] = (u & 0x80000000u) ? ~u : (u | 0x80000000u);
    }

#pragma unroll
    for (int j = 0; j < 16; ++j) hist[t + j * 256] = 0;
    if (t < 8) sh[t] = 0;
    __syncthreads();
#pragma unroll
    for (int j = 0; j < 16; ++j) atomicAdd(&hist[ov[j] >> 20], 1u);
    __syncthreads();

    unsigned cs = 0;
    {
        const int rot = (t >> 1) & 15;
#pragma unroll
        for (int q = 0; q < 16; ++q) cs += hist[t * 16 + ((q + rot) & 15)];
    }
    unsigned val = cs;
#pragma unroll
    for (int off = 1; off < 64; off <<= 1) {
        unsigned o = __shfl_down(val, off, 64);
        if (lane + off < 64) val += o;
    }
    if (lane == 0) wtot[wv] = val;
    __syncthreads();
    unsigned above_w = 0;
    for (int q = wv + 1; q < 4; ++q) above_w += wtot[q];
    unsigned Sincl = val + above_w;
    unsigned excl = Sincl - cs;
    if (excl < KNBR && Sincl >= KNBR) { sh[0] = t; sh[1] = (int)excl; }
    __syncthreads();
    if (t == 0) {
        int tstar = sh[0];
        unsigned run = (unsigned)sh[1];
        int B1 = -1; unsigned hcnt = 0;
        for (int q = 15; q >= 0; --q) {
            unsigned h = hist[tstar * 16 + q];
            if (run + h >= KNBR) { B1 = tstar * 16 + q; hcnt = h; break; }
            run += h;
        }
        sh[0] = B1; sh[1] = (int)run;
        int R1 = KNBR - (int)run;
        sh[7] = R1;
        sh[2] = ((int)hcnt > R1) ? 1 : 0;
    }
    __syncthreads();
    const unsigned B1 = (unsigned)sh[0];
    const int needRef = sh[2];
    const int R1 = sh[7];
    const int nab = sh[1];

#pragma unroll
    for (int j = 0; j < 16; ++j) {
        unsigned bb = ov[j] >> 20;
        if (bb > B1) { int p = atomicAdd(&sh[3], 1); idxo[pt * KNBR + p] = t + j * 256; }
        else if (bb == B1) {
            if (!needRef) { int p = atomicAdd(&sh[3], 1); idxo[pt * KNBR + p] = t + j * 256; }
            else { int q = atomicAdd(&sh[6], 1); if (q < 2048) { cov[q] = ov[j]; cidx[q] = t + j * 256; } }
        }
    }
    if (!needRef) return;
    __syncthreads();
    const int C = sh[6] < 2048 ? sh[6] : 2048;
    for (int j = t; j < C; j += 256) {
        unsigned myv = cov[j]; int myi = cidx[j];
        int rank = 0;
        for (int q = 0; q < C; ++q) {
            unsigned v = cov[q];
            rank += (v > myv || (v == myv && cidx[q] < myi)) ? 1 : 0;
        }
        if (rank < R1) idxo[pt * KNBR + nab + rank] = myi;
    }
}

// ---------------- Layer 1 via MFMA: conv1(6->64 VALU) + conv2(64->64 MFMA) + in-reg max, 2 pts/block --------
__global__ __launch_bounds__(256) void layer1_mfma_kernel(const float* __restrict__ x, const int* __restrict__ idx,
    const float* __restrict__ W1, const float* __restrict__ s1, const float* __restrict__ b1,
    const short* __restrict__ w2h, const short* __restrict__ w2l,
    const float* __restrict__ s2, const float* __restrict__ b2,
    unsigned* __restrict__ x1p)
{
    const int t = threadIdx.x;
    const int pt0 = blockIdx.x * 2;
    const int b = pt0 >> 12;
    const float* xb = x + b * 3 * N_PTS;
    const int lane = t & 63, w = t >> 6;
    const int cn = lane & 15, kg = lane >> 4;

    __shared__ int idxs[80];
    __shared__ float w1t[384];          // [6][64] transposed W1
    __shared__ float ctrv[2][64];
    __shared__ float nbrc[80][4];
    __shared__ float Abuf[5808];
    short* A_hi = (short*)Abuf;
    short* A_lo = A_hi + 80 * 72;

    if (t < 80) idxs[t] = idx[pt0 * KNBR + t];
    if (t < 64) {
#pragma unroll
        for (int j = 0; j < 6; ++j) w1t[j * 64 + t] = W1[t * 6 + j];
    }
    __syncthreads();
    if (t < 240) { int k = t / 3, j = t % 3; nbrc[k][j] = xb[j * N_PTS + idxs[k]]; }
    if (t < 128) {
        int p = t >> 6, o = t & 63;
        int n = (pt0 + p) & 4095;
        float cx = xb[n], cy = xb[N_PTS + n], cz = xb[2 * N_PTS + n];
        ctrv[p][o] = (w1t[192 + o] - w1t[o]) * cx + (w1t[256 + o] - w1t[64 + o]) * cy
                   + (w1t[320 + o] - w1t[128 + o]) * cz;
    }
    bf16x8 bh[2], bl[2];
#pragma unroll
    for (int kc = 0; kc < 2; ++kc) {
        int off = (w * 16 + cn) * 64 + kc * 32 + kg * 8;
        bh[kc] = *(const bf16x8*)(w2h + off);
        bl[kc] = *(const bf16x8*)(w2l + off);
    }
    __syncthreads();
    {
        const int o = t & 63;
        const float w0 = w1t[o], w1v = w1t[64 + o], w2v = w1t[128 + o];
        const float sv = s1[o], bv = b1[o];
        const float cv0 = ctrv[0][o], cv1 = ctrv[1][o];
#pragma unroll
        for (int r = 0; r < 20; ++r) {
            int k = (t >> 6) + r * 4;
            float v = w0 * nbrc[k][0] + w1v * nbrc[k][1] + w2v * nbrc[k][2] + (k >= KNBR ? cv1 : cv0);
            v = lrelu(v * sv + bv);
            unsigned u = __float_as_uint(v);
            unsigned hi = u & 0xFFFF0000u;
            A_hi[k * 72 + o] = (short)(u >> 16);
            float rr = v - __uint_as_float(hi);
            A_lo[k * 72 + o] = (short)(__float_as_uint(rr) >> 16);
        }
    }
    __syncthreads();
    f32x4 acc[5];
#pragma unroll
    for (int mt = 0; mt < 5; ++mt) {
        f32x4 a = {0.f, 0.f, 0.f, 0.f};
#pragma unroll
        for (int kc = 0; kc < 2; ++kc) {
            int ao = (mt * 16 + cn) * 72 + kc * 32 + kg * 8;
            bf16x8 ah = *(const bf16x8*)(A_hi + ao);
            bf16x8 al = *(const bf16x8*)(A_lo + ao);
            a = __builtin_amdgcn_mfma_f32_16x16x32_bf16(al, bh[kc], a, 0, 0, 0);
            a = __builtin_amdgcn_mfma_f32_16x16x32_bf16(ah, bl[kc], a, 0, 0, 0);
            a = __builtin_amdgcn_mfma_f32_16x16x32_bf16(ah, bh[kc], a, 0, 0, 0);
        }
        acc[mt] = a;
    }
    const int o1 = w * 16 + cn;
    const float sB = s2[o1], bB = b2[o1];
    float m0 = -1e30f, m1 = -1e30f;
#pragma unroll
    for (int mt = 0; mt < 5; ++mt)
#pragma unroll
        for (int reg = 0; reg < 4; ++reg) {
            int row = mt * 16 + kg * 4 + reg;
            float v = lrelu(acc[mt][reg] * sB + bB);
            if (row < KNBR) m0 = fmaxf(m0, v); else m1 = fmaxf(m1, v);
        }
    m0 = fmaxf(m0, __shfl_xor(m0, 16, 64));
    m0 = fmaxf(m0, __shfl_xor(m0, 32, 64));
    m1 = fmaxf(m1, __shfl_xor(m1, 16, 64));
    m1 = fmaxf(m1, __shfl_xor(m1, 32, 64));
    if (kg == 0) {
        x1p[pt0 * 64 + o1] = packbf(m0);
        x1p[(pt0 + 1) * 64 + o1] = packbf(m1);
    }
}

// ---------------- merged prep: all weight splits + ctr-weight transpose ----------------
__global__ __launch_bounds__(256) void prep_all(
    const float* __restrict__ W2, const float* __restrict__ W3,
    const float* __restrict__ W4, const float* __restrict__ W5,
    const float* __restrict__ W6, const float* __restrict__ W7,
    const float* __restrict__ W8, const float* __restrict__ W9,
    short* __restrict__ w2h, short* __restrict__ w2l,
    short* __restrict__ w3h, short* __restrict__ w3l,
    short* __restrict__ w4h, short* __restrict__ w4l,
    short* __restrict__ w5h, short* __restrict__ w5l,
    float* __restrict__ wdt3, float* __restrict__ wdt5,
    short* __restrict__ w6h, short* __restrict__ w6l,
    short* __restrict__ w7h, short* __restrict__ w7l,
    short* __restrict__ w8h, short* __restrict__ w8l,
    short* __restrict__ w9h, short* __restrict__ w9l)
{
    int e = blockIdx.x * 256 + threadIdx.x;
    if (e < 4096) {
        int o = e >> 6, i = e & 63;
        float a = W3[o * 128 + i];
        short h = bf16_rn(a);
        w3h[e] = h; w3l[e] = bf16_rn(a - bf16f(h));
        wdt3[i * 64 + o] = W3[o * 128 + 64 + i] - a;
        float c = W4[o * 64 + i];
        h = bf16_rn(c);
        w4h[e] = h; w4l[e] = bf16_rn(c - bf16f(h));
        float d = W5[o * 128 + i];
        h = bf16_rn(d);
        w5h[e] = h; w5l[e] = bf16_rn(d - bf16f(h));
        wdt5[i * 64 + o] = W5[o * 128 + 64 + i] - d;
        float e2 = W2[o * 64 + i];
        h = bf16_rn(e2);
        w2h[e] = h; w2l[e] = bf16_rn(e2 - bf16f(h));
    }
    {
        float v; short* dh; short* dl; int di;
        if (e < 196608) {
            v = W6[e]; dh = w6h; dl = w6l; di = e;
        } else if (e < 294912) {
            int ee = e - 196608;
            int o = ee / 192, k = ee - o * 192;
            v = W7[o * 1216 + 1024 + k]; dh = w7h; dl = w7l; di = ee;
        } else if (e < 425984) {
            int ee = e - 294912;
            v = W8[ee]; dh = w8h; dl = w8l; di = ee;
        } else if (e < 442368) {
            int ee = e - 425984;
            int o = ee >> 8, k = ee & 255;
            v = (o < 63) ? W9[o * 256 + k] : 0.0f;
            dh = w9h; dl = w9l; di = ee;
        } else return;
        short h = bf16_rn(v);
        dh[di] = h; dl[di] = bf16_rn(v - bf16f(h));
    }
}

// ---------------- Edge layers via MFMA (split-bf16), packed input, in-reg max, 2 points/block, M=80 --------
template<int HAS2>
__global__ __launch_bounds__(256) void edge_mfma_kernel(const unsigned* __restrict__ srcp, const int* __restrict__ idx,
    const short* __restrict__ wah, const short* __restrict__ wal, const float* __restrict__ wdt,
    const float* __restrict__ sa, const float* __restrict__ ba,
    const short* __restrict__ wbh, const short* __restrict__ wbl,
    const float* __restrict__ sb, const float* __restrict__ bb,
    unsigned* __restrict__ xpout)
{
    const int t = threadIdx.x;
    const int pt0 = blockIdx.x * 2;
    const int b = pt0 >> 12;
    const int lane = t & 63, w = t >> 6;
    const int cn = lane & 15, kg = lane >> 4;

    __shared__ int idxs[80];
    __shared__ float ctr1[2][64];
    __shared__ float part[2][2][64];
    __shared__ float Abuf[5808];
    short* A_hi = (short*)Abuf;
    short* A_lo = A_hi + 80 * 72;

    if (t < 80) idxs[t] = idx[pt0 * KNBR + t];
    if (t >= 128) {
        int p = (t >> 6) & 1; int i = t & 63;
        unsigned u = srcp[(pt0 + p) * 64 + i];
        ctr1[p][i] = bf16f((short)(u >> 16)) + bf16f((short)u);
    }
    __syncthreads();

    bf16x8 bh[2], bl[2];
#pragma unroll
    for (int kc = 0; kc < 2; ++kc) {
        int off = (w * 16 + cn) * 64 + kc * 32 + kg * 8;
        bh[kc] = *(const bf16x8*)(wah + off);
        bl[kc] = *(const bf16x8*)(wal + off);
    }

    // gather packed neighbors -> unpack to hi/lo LDS planes (2 shifts/elem)
    {
        const int r0 = t >> 4, c4 = (t & 15) * 4;
#pragma unroll
        for (int r = 0; r < 5; ++r) {
            int row = r * 16 + r0;
            uint4 v = *(const uint4*)(srcp + (size_t)(b * N_PTS + idxs[row]) * 64 + c4);
            short4 h, l;
            h.x = (short)(v.x >> 16); l.x = (short)v.x;
            h.y = (short)(v.y >> 16); l.y = (short)v.y;
            h.z = (short)(v.z >> 16); l.z = (short)v.z;
            h.w = (short)(v.w >> 16); l.w = (short)v.w;
            *(short4*)(A_hi + row * 72 + c4) = h;
            *(short4*)(A_lo + row * 72 + c4) = l;
        }
    }
    // ctrv partials across all 256 threads (32 FMAs each)
    {
        int p = t >> 7, half = (t >> 6) & 1, o = t & 63;
        const float* wp = wdt + half * 32 * 64 + o;
        float s = 0.0f;
#pragma unroll 8
        for (int i = 0; i < 32; ++i) s = fmaf(wp[i * 64], ctr1[p][half * 32 + i], s);
        part[p][half][o] = s;
    }
    __syncthreads();

    f32x4 acc[5];
#pragma unroll
    for (int mt = 0; mt < 5; ++mt) {
        f32x4 a = {0.f, 0.f, 0.f, 0.f};
#pragma unroll
        for (int kc = 0; kc < 2; ++kc) {
            int ao = (mt * 16 + cn) * 72 + kc * 32 + kg * 8;
            bf16x8 ah = *(const bf16x8*)(A_hi + ao);
            bf16x8 al = *(const bf16x8*)(A_lo + ao);
            a = __builtin_amdgcn_mfma_f32_16x16x32_bf16(al, bh[kc], a, 0, 0, 0);
            a = __builtin_amdgcn_mfma_f32_16x16x32_bf16(ah, bl[kc], a, 0, 0, 0);
            a = __builtin_amdgcn_mfma_f32_16x16x32_bf16(ah, bh[kc], a, 0, 0, 0);
        }
        acc[mt] = a;
    }

    const int o1 = w * 16 + cn;
    const float cv0 = part[0][0][o1] + part[0][1][o1];
    const float cv1 = part[1][0][o1] + part[1][1][o1];
    const float sA = sa[o1], bA = ba[o1];

    if (HAS2) {
        __syncthreads();   // all MFMA reads of A done before overwrite
#pragma unroll
        for (int mt = 0; mt < 5; ++mt) {
#pragma unroll
            for (int reg = 0; reg < 4; ++reg) {
                int row = mt * 16 + kg * 4 + reg;
                float v = lrelu((acc[mt][reg] + (row >= KNBR ? cv1 : cv0)) * sA + bA);
                unsigned u = __float_as_uint(v);
                unsigned hi = u & 0xFFFF0000u;
                A_hi[row * 72 + o1] = (short)(u >> 16);
                float rr = v - __uint_as_float(hi);
                A_lo[row * 72 + o1] = (short)(__float_as_uint(rr) >> 16);
            }
        }
        __syncthreads();
#pragma unroll
        for (int kc = 0; kc < 2; ++kc) {
            int off = (w * 16 + cn) * 64 + kc * 32 + kg * 8;
            bh[kc] = *(const bf16x8*)(wbh + off);
            bl[kc] = *(const bf16x8*)(wbl + off);
        }
#pragma unroll
        for (int mt = 0; mt < 5; ++mt) {
            f32x4 a = {0.f, 0.f, 0.f, 0.f};
#pragma unroll
            for (int kc = 0; kc < 2; ++kc) {
                int ao = (mt * 16 + cn) * 72 + kc * 32 + kg * 8;
                bf16x8 ah = *(const bf16x8*)(A_hi + ao);
                bf16x8 al = *(const bf16x8*)(A_lo + ao);
                a = __builtin_amdgcn_mfma_f32_16x16x32_bf16(al, bh[kc], a, 0, 0, 0);
                a = __builtin_amdgcn_mfma_f32_16x16x32_bf16(ah, bl[kc], a, 0, 0, 0);
                a = __builtin_amdgcn_mfma_f32_16x16x32_bf16(ah, bh[kc], a, 0, 0, 0);
            }
            acc[mt] = a;
        }
        const float sB = sb[o1], bB = bb[o1];
        float m0 = -1e30f, m1 = -1e30f;
#pragma unroll
        for (int mt = 0; mt < 5; ++mt)
#pragma unroll
            for (int reg = 0; reg < 4; ++reg) {
                int row = mt * 16 + kg * 4 + reg;
                float v = lrelu(acc[mt][reg] * sB + bB);
                if (row < KNBR) m0 = fmaxf(m0, v); else m1 = fmaxf(m1, v);
            }
        m0 = fmaxf(m0, __shfl_xor(m0, 16, 64));
        m0 = fmaxf(m0, __shfl_xor(m0, 32, 64));
        m1 = fmaxf(m1, __shfl_xor(m1, 16, 64));
        m1 = fmaxf(m1, __shfl_xor(m1, 32, 64));
        if (kg == 0) {
            xpout[pt0 * 64 + o1] = packbf(m0);
            xpout[(pt0 + 1) * 64 + o1] = packbf(m1);
        }
    } else {
        float m0 = -1e30f, m1 = -1e30f;
#pragma unroll
        for (int mt = 0; mt < 5; ++mt)
#pragma unroll
            for (int reg = 0; reg < 4; ++reg) {
                int row = mt * 16 + kg * 4 + reg;
                float v = lrelu((acc[mt][reg] + (row >= KNBR ? cv1 : cv0)) * sA + bA);
                if (row < KNBR) m0 = fmaxf(m0, v); else m1 = fmaxf(m1, v);
            }
        m0 = fmaxf(m0, __shfl_xor(m0, 16, 64));
        m0 = fmaxf(m0, __shfl_xor(m0, 32, 64));
        m1 = fmaxf(m1, __shfl_xor(m1, 16, 64));
        m1 = fmaxf(m1, __shfl_xor(m1, 32, 64));
        if (kg == 0) {
            xpout[pt0 * 64 + o1] = packbf(m0);
            xpout[(pt0 + 1) * 64 + o1] = packbf(m1);
        }
    }
}

// ---------------- Split-bf16 MFMA GEMM, fused epilogues ----------------
// MODE 0: conv6 (A=x123p K=192, lrelu, per-block col-max -> gpart)
// MODE 3: conv9 (A=h8p K=256, +b9, transposed fp32 store, col<63)
template<int MODE, int MT, int NT, int KD, int NTOT>
__global__ __launch_bounds__(256) void gemm_mfma(
    const unsigned* __restrict__ A0, const unsigned* __restrict__ A1, const unsigned* __restrict__ A2,
    const short* __restrict__ Bh, const short* __restrict__ Bl,
    const float* __restrict__ sv, const float* __restrict__ bvv,
    const float* __restrict__ extra, void* __restrict__ outp)
{
    const int t = threadIdx.x;
    const int w = t >> 6, lane = t & 63;
    const int cn = lane & 15, kg = lane >> 4;
    const int m0 = blockIdx.x * (MT * 16);
    const int n0 = blockIdx.y * (NT * 64);

    __shared__ __align__(16) short Abuf2[2 * MT * 16 * 40];
    short* A_hi = Abuf2;
    short* A_lo = Abuf2 + MT * 16 * 40;

    f32x4 acc[MT][NT];
#pragma unroll
    for (int mt = 0; mt < MT; ++mt)
#pragma unroll
        for (int nt = 0; nt < NT; ++nt) acc[mt][nt] = (f32x4){0.f, 0.f, 0.f, 0.f};

    for (int kc = 0; kc < KD / 32; ++kc) {
        {
            const int kq = (t & 7) * 4;
            const int r0 = t >> 3;
#pragma unroll
            for (int rr = 0; rr < (MT * 16) / 32; ++rr) {
                int row = r0 + rr * 32;
                int gk = kc * 32 + kq;
                uint4 v;
                if (MODE == 0) {
                    const unsigned* srcp = (gk < 64) ? A0 : ((gk < 128) ? A1 : A2);
                    v = *(const uint4*)(srcp + (size_t)(m0 + row) * 64 + (gk & 63));
                } else {
                    v = *(const uint4*)(A0 + (size_t)(m0 + row) * KD + gk);
                }
                short4 h, l;
                h.x = (short)(v.x >> 16); l.x = (short)v.x;
                h.y = (short)(v.y >> 16); l.y = (short)v.y;
                h.z = (short)(v.z >> 16); l.z = (short)v.z;
                h.w = (short)(v.w >> 16); l.w = (short)v.w;
                *(short4*)(A_hi + row * 40 + kq) = h;
                *(short4*)(A_lo + row * 40 + kq) = l;
            }
        }
        __syncthreads();
        bf16x8 bh[NT], bl[NT];
#pragma unroll
        for (int nt = 0; nt < NT; ++nt) {
            int col = n0 + (w * NT + nt) * 16 + cn;
            int boff = col * KD + kc * 32 + kg * 8;
            bh[nt] = *(const bf16x8*)(Bh + boff);
            bl[nt] = *(const bf16x8*)(Bl + boff);
        }
#pragma unroll
        for (int mt = 0; mt < MT; ++mt) {
            int ao = (mt * 16 + cn) * 40 + kg * 8;
            bf16x8 ah = *(const bf16x8*)(A_hi + ao);
            bf16x8 al = *(const bf16x8*)(A_lo + ao);
#pragma unroll
            for (int nt = 0; nt < NT; ++nt) {
                acc[mt][nt] = __builtin_amdgcn_mfma_f32_16x16x32_bf16(al, bh[nt], acc[mt][nt], 0, 0, 0);
                acc[mt][nt] = __builtin_amdgcn_mfma_f32_16x16x32_bf16(ah, bl[nt], acc[mt][nt], 0, 0, 0);
                acc[mt][nt] = __builtin_amdgcn_mfma_f32_16x16x32_bf16(ah, bh[nt], acc[mt][nt], 0, 0, 0);
            }
        }
        __syncthreads();
    }

    if (MODE == 0) {
        float* gp = (float*)outp;
#pragma unroll
        for (int nt = 0; nt < NT; ++nt) {
            int col = n0 + (w * NT + nt) * 16 + cn;
            float s = sv[col], bb = bvv[col];
            float mx = -1e30f;
#pragma unroll
            for (int mt = 0; mt < MT; ++mt)
#pragma unroll
                for (int r = 0; r < 4; ++r) mx = fmaxf(mx, lrelu(acc[mt][nt][r] * s + bb));
            mx = fmaxf(mx, __shfl_xor(mx, 16, 64));
            mx = fmaxf(mx, __shfl_xor(mx, 32, 64));
            if (kg == 0) gp[blockIdx.x * NTOT + col] = mx;
        }
    } else {
        float* of = (float*)outp;
        const int b = m0 >> 12;
        const int nrow0 = m0 & 4095;
        int col = w * 16 + cn;
        if (col < 63) {
            float bb = bvv[col];
#pragma unroll
            for (int mt = 0; mt < MT; ++mt) {
                float4 o4;
                o4.x = acc[mt][0][0] + bb; o4.y = acc[mt][0][1] + bb;
                o4.z = acc[mt][0][2] + bb; o4.w = acc[mt][0][3] + bb;
                *(float4*)(of + (size_t)(b * 63 + col) * N_PTS + nrow0 + mt * 16 + kg * 4) = o4;
            }
        }
    }
}

// ---------------- MODE 2-style GEMM (contiguous packed A), packed output via LDS transpose ----------------
template<int MODE, int MT, int NT, int KD, int NTOT>
__global__ __launch_bounds__(256) void gemm_mfma_t(
    const unsigned* __restrict__ A0,
    const short* __restrict__ Bh, const short* __restrict__ Bl,
    const float* __restrict__ sv, const float* __restrict__ bvv,
    const float* __restrict__ extra, unsigned* __restrict__ op)
{
    const int t = threadIdx.x;
    const int w = t >> 6, lane = t & 63;
    const int cn = lane & 15, kg = lane >> 4;
    const int m0 = blockIdx.x * (MT * 16);
    const int n0 = blockIdx.y * (NT * 64);

    __shared__ __align__(16) short Abuf2[2 * MT * 16 * 40 > 2 * 16 * 132 * 2 ? 2 * MT * 16 * 40 : 2 * 16 * 132 * 2];
    short* A_hi = Abuf2;
    short* A_lo = Abuf2 + MT * 16 * 40;

    f32x4 acc[MT][NT];
#pragma unroll
    for (int mt = 0; mt < MT; ++mt)
#pragma unroll
        for (int nt = 0; nt < NT; ++nt) acc[mt][nt] = (f32x4){0.f, 0.f, 0.f, 0.f};

    for (int kc = 0; kc < KD / 32; ++kc) {
        {
            const int kq = (t & 7) * 4;
            const int r0 = t >> 3;
#pragma unroll
            for (int rr = 0; rr < (MT * 16) / 32; ++rr) {
                int row = r0 + rr * 32;
                int gk = kc * 32 + kq;
                uint4 v = *(const uint4*)(A0 + (size_t)(m0 + row) * KD + gk);
                short4 h, l;
                h.x = (short)(v.x >> 16); l.x = (short)v.x;
                h.y = (short)(v.y >> 16); l.y = (short)v.y;
                h.z = (short)(v.z >> 16); l.z = (short)v.z;
                h.w = (short)(v.w >> 16); l.w = (short)v.w;
                *(short4*)(A_hi + row * 40 + kq) = h;
                *(short4*)(A_lo + row * 40 + kq) = l;
            }
        }
        __syncthreads();
        bf16x8 bh[NT], bl[NT];
#pragma unroll
        for (int nt = 0; nt < NT; ++nt) {
            int col = n0 + (w * NT + nt) * 16 + cn;
            int boff = col * KD + kc * 32 + kg * 8;
            bh[nt] = *(const bf16x8*)(Bh + boff);
            bl[nt] = *(const bf16x8*)(Bl + boff);
        }
#pragma unroll
        for (int mt = 0; mt < MT; ++mt) {
            int ao = (mt * 16 + cn) * 40 + kg * 8;
            bf16x8 ah = *(const bf16x8*)(A_hi + ao);
            bf16x8 al = *(const bf16x8*)(A_lo + ao);
#pragma unroll
            for (int nt = 0; nt < NT; ++nt) {
                acc[mt][nt] = __builtin_amdgcn_mfma_f32_16x16x32_bf16(al, bh[nt], acc[mt][nt], 0, 0, 0);
                acc[mt][nt] = __builtin_amdgcn_mfma_f32_16x16x32_bf16(ah, bl[nt], acc[mt][nt], 0, 0, 0);
                acc[mt][nt] = __builtin_amdgcn_mfma_f32_16x16x32_bf16(ah, bh[nt], acc[mt][nt], 0, 0, 0);
            }
        }
        __syncthreads();
    }

    unsigned* T = (unsigned*)Abuf2;
    const int b = m0 >> 12;
#pragma unroll
    for (int mt = 0; mt < MT; ++mt) {
#pragma unroll
        for (int nt = 0; nt < NT; ++nt) {
            int col = n0 + (w * NT + nt) * 16 + cn;
            float s = sv[col], bb = bvv[col];
            float cc = (MODE == 1) ? extra[b * 512 + col] : 0.0f;
#pragma unroll
            for (int r = 0; r < 4; ++r) {
                float v = lrelu((acc[mt][nt][r] + cc) * s + bb);
                T[(kg * 4 + r) * 132 + (w * NT + nt) * 16 + cn] = pack_trunc(v);
            }
        }
        __syncthreads();
        {
            int row = t >> 4, c0 = (t & 15) * 8;
            uint4 u0 = *(uint4*)(T + row * 132 + c0);
            uint4 u1 = *(uint4*)(T + row * 132 + c0 + 4);
            int grow = m0 + mt * 16 + row;
            *(uint4*)(op + (size_t)grow * NTOT + n0 + c0) = u0;
            *(uint4*)(op + (size_t)grow * NTOT + n0 + c0 + 4) = u1;
        }
        __syncthreads();
    }
}

// ---------------- MODE 1 GEMM (three packed x-arrays), +c7 epilogue, packed output ----------------
template<int MT, int NT, int KD, int NTOT>
__global__ __launch_bounds__(256) void gemm_mfma_c7(
    const unsigned* __restrict__ A0, const unsigned* __restrict__ A1, const unsigned* __restrict__ A2,
    const short* __restrict__ Bh, const short* __restrict__ Bl,
    const float* __restrict__ sv, const float* __restrict__ bvv,
    const float* __restrict__ extra, unsigned* __restrict__ op)
{
    const int t = threadIdx.x;
    const int w = t >> 6, lane = t & 63;
    const int cn = lane & 15, kg = lane >> 4;
    const int m0 = blockIdx.x * (MT * 16);
    const int n0 = blockIdx.y * (NT * 64);

    __shared__ __align__(16) short Abuf2[2 * MT * 16 * 40 > 2 * 16 * 132 * 2 ? 2 * MT * 16 * 40 : 2 * 16 * 132 * 2];
    short* A_hi = Abuf2;
    short* A_lo = Abuf2 + MT * 16 * 40;

    f32x4 acc[MT][NT];
#pragma unroll
    for (int mt = 0; mt < MT; ++mt)
#pragma unroll
        for (int nt = 0; nt < NT; ++nt) acc[mt][nt] = (f32x4){0.f, 0.f, 0.f, 0.f};

    for (int kc = 0; kc < KD / 32; ++kc) {
        {
            const int kq = (t & 7) * 4;
            const int r0 = t >> 3;
#pragma unroll
            for (int rr = 0; rr < (MT * 16) / 32; ++rr) {
                int row = r0 + rr * 32;
                int gk = kc * 32 + kq;
                const unsigned* srcp = (gk < 64) ? A0 : ((gk < 128) ? A1 : A2);
                uint4 v = *(const uint4*)(srcp + (size_t)(m0 + row) * 64 + (gk & 63));
                short4 h, l;
                h.x = (short)(v.x >> 16); l.x = (short)v.x;
                h.y = (short)(v.y >> 16); l.y = (short)v.y;
                h.z = (short)(v.z >> 16); l.z = (short)v.z;
                h.w = (short)(v.w >> 16); l.w = (short)v.w;
                *(short4*)(A_hi + row * 40 + kq) = h;
                *(short4*)(A_lo + row * 40 + kq) = l;
            }
        }
        __syncthreads();
        bf16x8 bh[NT], bl[NT];
#pragma unroll
        for (int nt = 0; nt < NT; ++nt) {
            int col = n0 + (w * NT + nt) * 16 + cn;
            int boff = col * KD + kc * 32 + kg * 8;
            bh[nt] = *(const bf16x8*)(Bh + boff);
            bl[nt] = *(const bf16x8*)(Bl + boff);
        }
#pragma unroll
        for (int mt = 0; mt < MT; ++mt) {
            int ao = (mt * 16 + cn) * 40 + kg * 8;
            bf16x8 ah = *(const bf16x8*)(A_hi + ao);
            bf16x8 al = *(const bf16x8*)(A_lo + ao);
#pragma unroll
            for (int nt = 0; nt < NT; ++nt) {
                acc[mt][nt] = __builtin_amdgcn_mfma_f32_16x16x32_bf16(al, bh[nt], acc[mt][nt], 0, 0, 0);
                acc[mt][nt] = __builtin_amdgcn_mfma_f32_16x16x32_bf16(ah, bl[nt], acc[mt][nt], 0, 0, 0);
                acc[mt][nt] = __builtin_amdgcn_mfma_f32_16x16x32_bf16(ah, bh[nt], acc[mt][nt], 0, 0, 0);
            }
        }
        __syncthreads();
    }

    unsigned* T = (unsigned*)Abuf2;
    const int b = m0 >> 12;
#pragma unroll
    for (int mt = 0; mt < MT; ++mt) {
#pragma unroll
        for (int nt = 0; nt < NT; ++nt) {
            int col = n0 + (w * NT + nt) * 16 + cn;
            float s = sv[col], bb = bvv[col];
            float cc = extra[b * 512 + col];
#pragma unroll
            for (int r = 0; r < 4; ++r) {
                float v = lrelu((acc[mt][nt][r] + cc) * s + bb);
                T[(kg * 4 + r) * 132 + (w * NT + nt) * 16 + cn] = pack_trunc(v);
            }
        }
        __syncthreads();
        {
            int row = t >> 4, c0 = (t & 15) * 8;
            uint4 u0 = *(uint4*)(T + row * 132 + c0);
            uint4 u1 = *(uint4*)(T + row * 132 + c0 + 4);
            int grow = m0 + mt * 16 + row;
            *(uint4*)(op + (size_t)grow * NTOT + n0 + c0) = u0;
            *(uint4*)(op + (size_t)grow * NTOT + n0 + c0 + 4) = u1;
        }
        __syncthreads();
    }
}

__global__ __launch_bounds__(256) void greduce_kernel(const float* __restrict__ gpart, float* __restrict__ g)
{
    int tid = blockIdx.x * 256 + threadIdx.x;   // 4096
    int b = tid >> 10, o = tid & 1023;
    float m = -1e30f;
    for (int q = 0; q < 32; ++q) m = fmaxf(m, gpart[(b * 32 + q) * 1024 + o]);
    g[tid] = m;
}

__global__ __launch_bounds__(256) void c7_kernel(const float* __restrict__ g, const float* __restrict__ W7,
                                                 float* __restrict__ c7)
{
    int tid = blockIdx.x * 256 + threadIdx.x;   // 2048
    int b = tid >> 9, o = tid & 511;
    const float* gb = g + b * 1024;
    const float* wr = W7 + o * 1216;
    float s = 0.0f;
    for (int i = 0; i < 1024; i += 4) {
        float4 wv4 = *reinterpret_cast<const float4*>(&wr[i]);
        float4 gv4 = *reinterpret_cast<const float4*>(&gb[i]);
        s += wv4.x * gv4.x + wv4.y * gv4.y + wv4.z * gv4.z + wv4.w * gv4.w;
    }
    c7[tid] = s;
}

extern "C" void kernel_launch(void* const* d_in, const int* in_sizes, int n_in,
                              void* d_out, int out_size, void* d_ws, size_t ws_size,
                              hipStream_t stream)
{
    const float* x  = (const float*)d_in[0];
    const float* W1 = (const float*)d_in[1];
    const float* s1 = (const float*)d_in[2];
    const float* b1 = (const float*)d_in[3];
    const float* W2 = (const float*)d_in[4];
    const float* s2 = (const float*)d_in[5];
    const float* b2 = (const float*)d_in[6];
    const float* W3 = (const float*)d_in[7];
    const float* s3 = (const float*)d_in[8];
    const float* b3 = (const float*)d_in[9];
    const float* W4 = (const float*)d_in[10];
    const float* s4 = (const float*)d_in[11];
    const float* b4 = (const float*)d_in[12];
    const float* W5 = (const float*)d_in[13];
    const float* s5 = (const float*)d_in[14];
    const float* b5 = (const float*)d_in[15];
    const float* W6 = (const float*)d_in[16];
    const float* s6 = (const float*)d_in[17];
    const float* b6 = (const float*)d_in[18];
    const float* W7 = (const float*)d_in[19];
    const float* s7 = (const float*)d_in[20];
    const float* b7 = (const float*)d_in[21];
    const float* W8 = (const float*)d_in[22];
    const float* s8 = (const float*)d_in[23];
    const float* b8 = (const float*)d_in[24];
    const float* W9 = (const float*)d_in[25];
    const float* b9 = (const float*)d_in[26];

    char* ws = (char*)d_ws;
    int*      idx   = (int*)(ws);                      // 2.62 MB
    unsigned* x1p   = (unsigned*)(ws + 15204352);
    unsigned* x2p   = (unsigned*)(ws + 19398656);
    unsigned* x3p   = (unsigned*)(ws + 23592960);
    float*    gpart = (float*)(ws + 27787264);
    float*    g     = (float*)(ws + 28311552);
    float*    c7    = (float*)(ws + 28327936);
    short*    w3h   = (short*)(ws + 28336128);
    short*    w3l   = w3h + 4096;
    short*    w4h   = w3h + 8192;
    short*    w4l   = w3h + 12288;
    short*    w5h   = w3h + 16384;
    short*    w5l   = w3h + 20480;
    float*    wdt3  = (float*)(ws + 28385280);
    float*    wdt5  = (float*)(ws + 28401664);
    short*    w6h   = (short*)(ws + 28418048);
    short*    w6l   = (short*)(ws + 28811264);
    short*    w7h   = (short*)(ws + 29204480);
    short*    w7l   = (short*)(ws + 29401088);
    short*    w8h   = (short*)(ws + 29597696);
    short*    w8l   = (short*)(ws + 29859840);
    short*    w9h   = (short*)(ws + 30121984);
    short*    w9l   = (short*)(ws + 30154752);
    short*    w2h   = (short*)(ws + 30187520);
    short*    w2l   = (short*)(ws + 30195712);
    unsigned* h7p   = (unsigned*)(ws + 30408704);      // 33.55 MB -> ends 63963136
    unsigned* h8p   = (unsigned*)(ws);                 // aliases dead early buffers
    float*    outp  = (float*)d_out;

    knn_kernel<<<BATCH * N_PTS, 256, 0, stream>>>(x, idx);
    prep_all<<<1728, 256, 0, stream>>>(W2, W3, W4, W5, W6, W7, W8, W9,
        w2h, w2l, w3h, w3l, w4h, w4l, w5h, w5l, wdt3, wdt5,
        w6h, w6l, w7h, w7l, w8h, w8l, w9h, w9l);
    layer1_mfma_kernel<<<BATCH * N_PTS / 2, 256, 0, stream>>>(x, idx, W1, s1, b1, w2h, w2l, s2, b2, x1p);
    edge_mfma_kernel<1><<<BATCH * N_PTS / 2, 256, 0, stream>>>(x1p, idx, w3h, w3l, wdt3, s3, b3, w4h, w4l, s4, b4, x2p);
    edge_mfma_kernel<0><<<BATCH * N_PTS / 2, 256, 0, stream>>>(x2p, idx, w5h, w5l, wdt5, s5, b5, nullptr, nullptr, nullptr, nullptr, x3p);
    gemm_mfma<0, 8, 2, 192, 1024><<<dim3(128, 8), 256, 0, stream>>>(x1p, x2p, x3p, w6h, w6l, s6, b6, nullptr, gpart);
    greduce_kernel<<<16, 256, 0, stream>>>(gpart, g);
    c7_kernel<<<8, 256, 0, stream>>>(g, W7, c7);
    gemm_mfma_c7<8, 2, 192, 512><<<dim3(128, 4), 256, 0, stream>>>(x1p, x2p, x3p, w7h, w7l, s7, b7, c7, h7p);
    gemm_mfma_t<2, 4, 2, 512, 256><<<dim3(256, 2), 256, 0, stream>>>(h7p, w8h, w8l, s8, b8, nullptr, h8p);
    gemm_mfma<3, 4, 1, 256, 64><<<dim3(256, 1), 256, 0, stream>>>(h8p, nullptr, nullptr, w9h, w9l, nullptr, b9, nullptr, outp);
}